// Round 13
// baseline (253.590 us; speedup 1.0000x reference)
//
#include <hip/hip_runtime.h>
#include <hip/hip_fp16.h>
#include <math.h>

#define N_NODES 100000
#define E_EDGES 1600000
#define ETOT (E_EDGES + N_NODES)   // 1,700,000 with self-loops
#define NEG 0.2f
#define NB 782          // buckets: 128 nodes each
#define NREP 4          // cursor/segment replication (contention control)
#define SEG 704         // per-replica capacity: mean 511.5, sigma 22.6 -> +8.5 sigma
#define BCAP (NREP * SEG)
#define CHUNK 4096
#define NCHB ((E_EDGES + CHUNK - 1) / CHUNK)  // 391 binning blocks (real edges only)
#define GEMM1_BLOCKS ((N_NODES + 63) / 64)    // 1563
#define LOG2E 1.44269504f
#define SHIFT2 5.77078016f   // 4 * log2(e); cancels in softmax ratio

typedef _Float16 half8 __attribute__((ext_vector_type(8)));
typedef _Float16 half4v __attribute__((ext_vector_type(4)));
typedef _Float16 half2v __attribute__((ext_vector_type(2)));
typedef float floatx4 __attribute__((ext_vector_type(4)));

union H8I {
  half8 v;
  _Float16 e[8];
  half2v h2[4];
  int i[4];
};

__device__ __forceinline__ float elu(float v) { return v > 0.f ? v : (__expf(v) - 1.f); }

// packed fp16 score: sum(att * leakyrelu(a + r)) -> float   (att pre-scaled by log2e)
__device__ __forceinline__ float score8(half8 a, half8 r, half8 av) {
  half8 t = a + r;
  t = __builtin_elementwise_max(t, t * (_Float16)NEG);
#if __has_builtin(__builtin_amdgcn_fdot2)
  H8I u, w;
  u.v = t; w.v = av;
  float s = 0.f;
#pragma unroll
  for (int j = 0; j < 4; j++) s = __builtin_amdgcn_fdot2(u.h2[j], w.h2[j], s, false);
  return s;
#else
  half8 s8 = t * av;
  half4v s4 = __builtin_shufflevector(s8, s8, 0, 1, 2, 3) +
              __builtin_shufflevector(s8, s8, 4, 5, 6, 7);
  half2v s2 = __builtin_shufflevector(s4, s4, 0, 1) +
              __builtin_shufflevector(s4, s4, 2, 3);
  return (float)s2[0] + (float)s2[1];
#endif
}

// ===== fusedA: block-aggregated binning of REAL edges (blocks 0..NCHB-1) || pack =====
__global__ __launch_bounds__(256) void fusedA_kernel(
    const int* __restrict__ ei, unsigned* __restrict__ cursor,
    unsigned* __restrict__ bins,
    const float* __restrict__ W1l, const float* __restrict__ W1r,
    const float* __restrict__ b1l, const float* __restrict__ b1r,
    const float* __restrict__ W2l, const float* __restrict__ W2r,
    const float* __restrict__ b2l, const float* __restrict__ b2r,
    const float* __restrict__ att1, const float* __restrict__ att2,
    _Float16* __restrict__ Bperm, _Float16* __restrict__ B2perm,
    float* __restrict__ biascat, float* __restrict__ bias2cat,
    _Float16* __restrict__ att1h, _Float16* __restrict__ att2h) {
  int t = threadIdx.x;
  if (blockIdx.x < NCHB) {
    __shared__ unsigned cnt[NB];
    __shared__ unsigned base[NB];
    int rep = blockIdx.x & (NREP - 1);
    for (int b = t; b < NB; b += 256) cnt[b] = 0;
    __syncthreads();
    int e0 = blockIdx.x * CHUNK;
    int dstr[CHUNK / 256];
#pragma unroll
    for (int i = 0; i < CHUNK / 256; i++) {
      int e = e0 + i * 256 + t;
      int dst = 0;
      if (e < E_EDGES) {
        dst = ei[E_EDGES + e];
        atomicAdd(&cnt[dst >> 7], 1u);
      }
      dstr[i] = dst;
    }
    __syncthreads();
    for (int b = t; b < NB; b += 256) {
      unsigned c = cnt[b];
      base[b] = c ? atomicAdd(&cursor[rep * NB + b], c) : 0u;
      cnt[b] = 0;
    }
    __syncthreads();
#pragma unroll
    for (int i = 0; i < CHUNK / 256; i++) {
      int e = e0 + i * 256 + t;
      if (e < E_EDGES) {
        int dst = dstr[i];
        int src = ei[e];
        int b = dst >> 7;
        unsigned off = atomicAdd(&cnt[b], 1u);
        bins[(size_t)b * BCAP + rep * SEG + base[b] + off] =
            ((unsigned)(dst & 127) << 17) | (unsigned)src;
      }
    }
  } else {
    int pb = blockIdx.x - NCHB;
    int gt = pb * 256 + t;
    int gstr = 20 * 256;
    for (int e = gt; e < 4096; e += gstr) {
      int nt = e >> 8, kt = (e >> 6) & 3, lane = e & 63;
      int n = nt * 16 + (lane & 15);
      int kb = kt * 32 + (lane >> 4) * 8;
#pragma unroll
      for (int j = 0; j < 8; j++) {
        int k = kb + j;
        float val = (n < 128) ? W1l[k * 128 + n] : W1r[k * 128 + (n - 128)];
        Bperm[(size_t)e * 8 + j] = (_Float16)val;
      }
    }
    for (int e = gt; e < 1024; e += gstr) {
      int nt = e >> 8, kt = (e >> 6) & 3, lane = e & 63;
      int n = nt * 16 + (lane & 15);
      int kb = kt * 32 + (lane >> 4) * 8;
#pragma unroll
      for (int j = 0; j < 8; j++) {
        int k = kb + j;
        float val = (n < 32) ? W2l[k * 32 + n] : W2r[k * 32 + (n - 32)];
        B2perm[(size_t)e * 8 + j] = (_Float16)val;
      }
    }
    if (pb == 0) {
      biascat[t] = (t < 128) ? b1l[t] : b1r[t - 128];
      if (t < 64) bias2cat[t] = (t < 32) ? b2l[t] : b2r[t - 32];
      if (t < 128) att1h[t] = (_Float16)(att1[t] * LOG2E);   // exp2 fold
      if (t < 32) att2h[t] = (_Float16)(att2[t] * LOG2E);
    }
  }
}

// ===== bucket-total scan: total[b] = sum_r cursor[r][b] + nodes_in_bucket(b) =====
__global__ __launch_bounds__(1024) void scan_buckets(const unsigned* __restrict__ cursor,
                                                     unsigned* __restrict__ bucket_base,
                                                     unsigned* __restrict__ rowptr) {
  __shared__ unsigned s[1024];
  int t = threadIdx.x;
  unsigned v = 0;
  if (t < NB) {
#pragma unroll
    for (int r = 0; r < NREP; r++) v += cursor[r * NB + t];
    int nib = N_NODES - (t << 7);
    v += (nib > 128) ? 128u : (unsigned)nib;   // self-loop slots
  }
  s[t] = v;
  __syncthreads();
  for (int off = 1; off < 1024; off <<= 1) {
    unsigned a = (t >= off) ? s[t - off] : 0u;
    __syncthreads();
    s[t] += a;
    __syncthreads();
  }
  if (t < NB) bucket_base[t] = s[t] - v;
  if (t == 0) { bucket_base[NB] = ETOT; rowptr[N_NODES] = ETOT; }
}

// ===== fusedB: per-bucket scatter + self-loop placement (blocks 0..NB-1) || GEMM1 =====
__global__ __launch_bounds__(256) void fusedB_kernel(
    const unsigned* __restrict__ bins, const unsigned* __restrict__ cursor,
    const unsigned* __restrict__ bucket_base,
    unsigned* __restrict__ rowptr, int* __restrict__ csr_src,
    const float* __restrict__ x, const _Float16* __restrict__ Bperm,
    const float* __restrict__ biascat,
    __half* __restrict__ xlh, __half* __restrict__ xrh) {
  __shared__ __align__(16) char smem[64 * 256];
  int t = threadIdx.x;
  if (blockIdx.x < NB) {
    unsigned* cnt = (unsigned*)smem;
    unsigned* pref = cnt + 128;
    int b = blockIdx.x;
    int nib = N_NODES - (b << 7);
    if (nib > 128) nib = 128;
    unsigned bbase = bucket_base[b];
    unsigned crs[NREP];
#pragma unroll
    for (int r = 0; r < NREP; r++) crs[r] = cursor[r * NB + b];
    const unsigned* bp = bins + (size_t)b * BCAP;
    if (t < 128) cnt[t] = 0;
    __syncthreads();
#pragma unroll
    for (int r = 0; r < NREP; r++)
      for (unsigned i = t; i < crs[r]; i += 256)
        atomicAdd(&cnt[bp[r * SEG + i] >> 17], 1u);
    __syncthreads();
    if (t < 128) pref[t] = (t < nib) ? cnt[t] + 1u : 0u;
    __syncthreads();
    for (int off = 1; off < 128; off <<= 1) {
      unsigned a = (t >= off && t < 128) ? pref[t - off] : 0u;
      __syncthreads();
      if (t < 128) pref[t] += a;
      __syncthreads();
    }
    if (t < 128) {
      unsigned tot = (t < nib) ? cnt[t] + 1u : 0u;
      unsigned excl = pref[t] - tot;
      pref[t] = excl;
      if (t < nib) {
        int n = (b << 7) + t;
        rowptr[n] = bbase + excl;
        csr_src[bbase + excl] = n;   // self-loop at slot 0
      }
      cnt[t] = 0;
    }
    __syncthreads();
#pragma unroll
    for (int r = 0; r < NREP; r++)
      for (unsigned i = t; i < crs[r]; i += 256) {
        unsigned en = bp[r * SEG + i];
        int j = (int)(en >> 17);
        unsigned off = atomicAdd(&cnt[j], 1u);
        csr_src[bbase + pref[j] + 1u + off] = (int)(en & 0x1FFFFu);
      }
  } else {
    // ---- GEMM1: x[N,128]f32 (cvt in staging) @ [128,256]f16 -> xlh, xrh ----
    int base = (blockIdx.x - NB) * 64;
    {
      int row = t >> 2, c4 = t & 3;
      int grow = base + row;
      const float* gp = x + (size_t)grow * 128 + c4 * 32;
#pragma unroll
      for (int j = 0; j < 4; j++) {
        half8 v = {};
        if (grow < N_NODES) {
          float4 f0 = *(const float4*)(gp + j * 8);
          float4 f1 = *(const float4*)(gp + j * 8 + 4);
          v[0] = (_Float16)f0.x; v[1] = (_Float16)f0.y;
          v[2] = (_Float16)f0.z; v[3] = (_Float16)f0.w;
          v[4] = (_Float16)f1.x; v[5] = (_Float16)f1.y;
          v[6] = (_Float16)f1.z; v[7] = (_Float16)f1.w;
        }
        int off = row * 256 + ((((c4 * 4 + j) * 16)) ^ ((row & 7) << 4));
        *(half8*)(smem + off) = v;
      }
    }
    int wid = t >> 6, lane = t & 63;
    half8 bf[4][4];  // [ntl][kt]
#pragma unroll
    for (int ntl = 0; ntl < 4; ntl++)
#pragma unroll
      for (int kt = 0; kt < 4; kt++) {
        int f = (wid * 4 + ntl) * 4 + kt;
        bf[ntl][kt] = *(const half8*)(Bperm + ((size_t)f * 64 + lane) * 8);
      }
    floatx4 acc[4][4] = {};  // [mt][ntl]
    __syncthreads();
#pragma unroll
    for (int kt = 0; kt < 4; kt++) {
      half8 a[4];
#pragma unroll
      for (int mt = 0; mt < 4; mt++) {
        int row = mt * 16 + (lane & 15);
        int kchunk = kt * 4 + (lane >> 4);
        int off = row * 256 + ((kchunk * 16) ^ ((row & 7) << 4));
        a[mt] = *(const half8*)(smem + off);
      }
#pragma unroll
      for (int mt = 0; mt < 4; mt++)
#pragma unroll
        for (int ntl = 0; ntl < 4; ntl++)
          acc[mt][ntl] = __builtin_amdgcn_mfma_f32_16x16x32_f16(a[mt], bf[ntl][kt],
                                                                acc[mt][ntl], 0, 0, 0);
    }
#pragma unroll
    for (int mt = 0; mt < 4; mt++) {
#pragma unroll
      for (int i = 0; i < 4; i++) {
        int row = base + mt * 16 + (lane >> 4) * 4 + i;
        if (row >= N_NODES) continue;
#pragma unroll
        for (int ntl = 0; ntl < 4; ntl++) {
          int col = wid * 64 + ntl * 16 + (lane & 15);
          float v = acc[mt][ntl][i] + biascat[col];
          if (col < 128) xlh[(size_t)row * 128 + col] = __float2half_rn(v);
          else xrh[(size_t)row * 128 + (col - 128)] = __float2half_rn(v);
        }
      }
    }
  }
}

// ====== GEMM2 (MFMA): h1[N,128]f16 @ [128,64]f16 -> xl2h, xr2h (fp16) ======
__global__ __launch_bounds__(256) void gemm2_mfma(
    const __half* __restrict__ h1h, const _Float16* __restrict__ B2perm,
    const float* __restrict__ bias2cat,
    __half* __restrict__ xl2h, __half* __restrict__ xr2h) {
  __shared__ __align__(16) char smem[64 * 256];
  int t = threadIdx.x;
  int base = blockIdx.x * 64;
  {
    int row = t >> 2, c4 = t & 3;
    int grow = base + row;
    const char* gp = (const char*)(h1h + (size_t)grow * 128 + c4 * 32);
#pragma unroll
    for (int j = 0; j < 4; j++) {
      half8 v = {};
      if (grow < N_NODES) v = *(const half8*)(gp + j * 16);
      int off = row * 256 + ((((c4 * 4 + j) * 16)) ^ ((row & 7) << 4));
      *(half8*)(smem + off) = v;
    }
  }
  int wid = t >> 6, lane = t & 63;
  half8 bf[4];  // [kt]
#pragma unroll
  for (int kt = 0; kt < 4; kt++) {
    int f = wid * 4 + kt;
    bf[kt] = *(const half8*)(B2perm + ((size_t)f * 64 + lane) * 8);
  }
  floatx4 acc[4] = {};
  __syncthreads();
#pragma unroll
  for (int kt = 0; kt < 4; kt++) {
    half8 a[4];
#pragma unroll
    for (int mt = 0; mt < 4; mt++) {
      int row = mt * 16 + (lane & 15);
      int kchunk = kt * 4 + (lane >> 4);
      int off = row * 256 + ((kchunk * 16) ^ ((row & 7) << 4));
      a[mt] = *(const half8*)(smem + off);
    }
#pragma unroll
    for (int mt = 0; mt < 4; mt++)
      acc[mt] = __builtin_amdgcn_mfma_f32_16x16x32_f16(a[mt], bf[kt], acc[mt], 0, 0, 0);
  }
  int col = wid * 16 + (lane & 15);
  float bv = bias2cat[col];
#pragma unroll
  for (int mt = 0; mt < 4; mt++) {
#pragma unroll
    for (int i = 0; i < 4; i++) {
      int row = base + mt * 16 + (lane >> 4) * 4 + i;
      if (row >= N_NODES) continue;
      float v = acc[mt][i] + bv;
      if (col < 32) xl2h[(size_t)row * 32 + col] = __float2half_rn(v);
      else xr2h[(size_t)row * 32 + (col - 32)] = __float2half_rn(v);
    }
  }
}

// ===== L1 fused gather: 2 waves/node (64 ch each); 8 edges/slot-group; 2x ILP =====
// shifted no-max softmax: p = exp2(v' - SHIFT2), v' pre-scaled by log2e via att
__global__ __launch_bounds__(256) void l1_gather_kernel(
    const __half* __restrict__ xlh, const __half* __restrict__ xrh,
    const int* __restrict__ csr_src, const unsigned* __restrict__ rowptr,
    const _Float16* __restrict__ att1h, const float* __restrict__ bias,
    __half* __restrict__ h1h) {
  int wid = threadIdx.x >> 6;
  int lane = threadIdx.x & 63;
  int n = blockIdx.x * 2 + (wid >> 1);     // 2 nodes/block, 2 waves/node
  int half = wid & 1;
  int g = lane >> 3;                        // edge slot 0..7
  int c0 = half * 64 + (lane & 7) * 8;      // channel base (head = c0>>5)
  half8 rv = *(const half8*)(xrh + (size_t)n * 128 + c0);
  half8 av = *(const half8*)(att1h + c0);
  unsigned beg = rowptr[n], end = rowptr[n + 1];
  unsigned deg = end - beg;
  unsigned niter = deg >> 3, rem = deg & 7;
  float d0 = 0.f, d1 = 0.f;
  H8I acc0, acc1;
  acc0.v = (half8){};
  acc1.v = (half8){};
  unsigned e = beg + g;
  unsigned i = 0;
  for (; i + 2 <= niter; i += 2, e += 16) {
    int s0 = csr_src[e];
    int s1 = csr_src[e + 8];
    H8I a0, a1;
    a0.v = *(const half8*)(xlh + (size_t)s0 * 128 + c0);
    a1.v = *(const half8*)(xlh + (size_t)s1 * 128 + c0);
    float v0 = score8(a0.v, rv, av);
    float v1 = score8(a1.v, rv, av);
    v0 += __shfl_xor(v0, 1);  v1 += __shfl_xor(v1, 1);
    v0 += __shfl_xor(v0, 2);  v1 += __shfl_xor(v1, 2);   // per-head (4-lane) score
    float p0 = exp2f(v0 - SHIFT2);
    float p1 = exp2f(v1 - SHIFT2);
    d0 += p0; d1 += p1;
    _Float16 ph0 = (_Float16)p0, ph1 = (_Float16)p1;
    half8 p80 = {ph0, ph0, ph0, ph0, ph0, ph0, ph0, ph0};
    half8 p81 = {ph1, ph1, ph1, ph1, ph1, ph1, ph1, ph1};
    acc0.v = p80 * a0.v + acc0.v;
    acc1.v = p81 * a1.v + acc1.v;
  }
  if (i < niter) {  // odd leftover full iteration
    int s0 = csr_src[e];
    H8I a0;
    a0.v = *(const half8*)(xlh + (size_t)s0 * 128 + c0);
    float v0 = score8(a0.v, rv, av);
    v0 += __shfl_xor(v0, 1);
    v0 += __shfl_xor(v0, 2);
    float p0 = exp2f(v0 - SHIFT2);
    d0 += p0;
    _Float16 ph0 = (_Float16)p0;
    half8 p80 = {ph0, ph0, ph0, ph0, ph0, ph0, ph0, ph0};
    acc0.v = p80 * a0.v + acc0.v;
    e += 8;
  }
  if (rem) {
    bool valid = (unsigned)g < rem;
    int s0 = csr_src[valid ? e : beg];
    H8I a0;
    a0.v = *(const half8*)(xlh + (size_t)s0 * 128 + c0);
    float v0 = score8(a0.v, rv, av);
    v0 += __shfl_xor(v0, 1);
    v0 += __shfl_xor(v0, 2);
    float p0 = valid ? exp2f(v0 - SHIFT2) : 0.f;
    d0 += p0;
    _Float16 ph0 = (_Float16)p0;
    half8 p80 = {ph0, ph0, ph0, ph0, ph0, ph0, ph0, ph0};
    acc0.v = p80 * a0.v + acc0.v;
  }
  // merge ILP states, then the 8 edge-slot groups (lane distance 8, 16, 32)
  float d = d0 + d1;
  H8I acc;
  acc.v = acc0.v + acc1.v;
#pragma unroll
  for (int msk = 8; msk <= 32; msk <<= 1) {
    d += __shfl_xor(d, msk);
    H8I o;
#pragma unroll
    for (int k = 0; k < 4; k++) o.i[k] = __shfl_xor(acc.i[k], msk);
    acc.v = acc.v + o.v;
  }
  if (g == 0) {   // lanes 0..7 cover this wave's 64 channels
    float inv = 1.f / d;
    H8I res;
#pragma unroll
    for (int j = 0; j < 8; j++)
      res.e[j] = (_Float16)elu((float)acc.e[j] * inv + bias[c0 + j]);
    *(half8*)(h1h + (size_t)n * 128 + c0) = res.v;
  }
}

// ===== L2 fused gather + final linear: 1 wave/node; 16 edges/iter; loop split =====
__global__ __launch_bounds__(256) void l2_gather_kernel(
    const __half* __restrict__ xl2h, const __half* __restrict__ xr2h,
    const int* __restrict__ csr_src, const unsigned* __restrict__ rowptr,
    const _Float16* __restrict__ att2h, const float* __restrict__ bias,
    const float* __restrict__ Wlin, const float* __restrict__ blin,
    float* __restrict__ out) {
  int wid = threadIdx.x >> 6;
  int lane = threadIdx.x & 63;
  int n = blockIdx.x * 4 + wid;
  if (n >= N_NODES) return;
  int g = lane >> 2;        // edge slot 0..15
  int q = lane & 3;         // channel slice: ch q*8..q*8+7
  int c0 = q * 8;
  half8 rv = *(const half8*)(xr2h + (size_t)n * 32 + c0);
  half8 av = *(const half8*)(att2h + c0);
  unsigned beg = rowptr[n], end = rowptr[n + 1];
  unsigned deg = end - beg;
  unsigned nfull = deg >> 4, rem = deg & 15;
  float d = 0.f;
  H8I acc;
  acc.v = (half8){};
  unsigned e = beg + g;
  for (unsigned i = 0; i < nfull; i++, e += 16) {
    int s = csr_src[e];
    H8I a;
    a.v = *(const half8*)(xl2h + (size_t)s * 32 + c0);
    float v = score8(a.v, rv, av);
    v += __shfl_xor(v, 1);
    v += __shfl_xor(v, 2);   // score over 4 lanes = 32 ch
    float p = exp2f(v - SHIFT2);
    d += p;
    _Float16 ph = (_Float16)p;
    half8 p8 = {ph, ph, ph, ph, ph, ph, ph, ph};
    acc.v = p8 * a.v + acc.v;
  }
  if (rem) {
    bool valid = (unsigned)g < rem;
    int s = csr_src[valid ? e : beg];
    H8I a;
    a.v = *(const half8*)(xl2h + (size_t)s * 32 + c0);
    float v = score8(a.v, rv, av);
    v += __shfl_xor(v, 1);
    v += __shfl_xor(v, 2);
    float p = valid ? exp2f(v - SHIFT2) : 0.f;
    d += p;
    _Float16 ph = (_Float16)p;
    half8 p8 = {ph, ph, ph, ph, ph, ph, ph, ph};
    acc.v = p8 * a.v + acc.v;
  }
  // merge the 16 edge-slot groups (lane distance 4, 8, 16, 32)
#pragma unroll
  for (int msk = 4; msk <= 32; msk <<= 1) {
    d += __shfl_xor(d, msk);
    H8I o;
#pragma unroll
    for (int k = 0; k < 4; k++) o.i[k] = __shfl_xor(acc.i[k], msk);
    acc.v = acc.v + o.v;
  }
  float inv = 1.f / d;
  float o0 = 0.f, o1 = 0.f;
#pragma unroll
  for (int j = 0; j < 8; j++) {
    float v = elu((float)acc.e[j] * inv + bias[c0 + j]);
    o0 = fmaf(v, Wlin[(c0 + j) * 2 + 0], o0);
    o1 = fmaf(v, Wlin[(c0 + j) * 2 + 1], o1);
  }
  o0 += __shfl_xor(o0, 1); o1 += __shfl_xor(o1, 1);
  o0 += __shfl_xor(o0, 2); o1 += __shfl_xor(o1, 2);
  if (lane == 0) {
    out[(size_t)n * 2 + 0] = o0 + blin[0];
    out[(size_t)n * 2 + 1] = o1 + blin[1];
  }
}

extern "C" void kernel_launch(void* const* d_in, const int* in_sizes, int n_in,
                              void* d_out, int out_size, void* d_ws, size_t ws_size,
                              hipStream_t stream) {
  const float* x     = (const float*)d_in[0];
  const int*   ei    = (const int*)d_in[1];
  const float* W1l   = (const float*)d_in[2];
  const float* b1l   = (const float*)d_in[3];
  const float* W1r   = (const float*)d_in[4];
  const float* b1r   = (const float*)d_in[5];
  const float* att1  = (const float*)d_in[6];
  const float* bias1 = (const float*)d_in[7];
  const float* W2l   = (const float*)d_in[8];
  const float* b2l   = (const float*)d_in[9];
  const float* W2r   = (const float*)d_in[10];
  const float* b2r   = (const float*)d_in[11];
  const float* att2  = (const float*)d_in[12];
  const float* bias2 = (const float*)d_in[13];
  const float* Wlin  = (const float*)d_in[14];
  const float* blin  = (const float*)d_in[15];
  float* out = (float*)d_out;

  // workspace layout
  __half* xl1h  = (__half*)d_ws;                        // N*128
  __half* xr1h  = xl1h + (size_t)N_NODES * 128;         // N*128
  __half* h1h   = xr1h + (size_t)N_NODES * 128;         // N*128
  __half* xl2h  = h1h + (size_t)N_NODES * 128;          // N*32
  __half* xr2h  = xl2h + (size_t)N_NODES * 32;          // N*32
  _Float16* Bperm  = (_Float16*)(xr2h + (size_t)N_NODES * 32);  // 32768
  _Float16* B2perm = Bperm + 32768;                     // 8192
  _Float16* att1h  = B2perm + 8192;                     // 128
  _Float16* att2h  = att1h + 128;                       // 32
  float* biascat   = (float*)(att2h + 32);              // 256
  float* bias2cat  = biascat + 256;                     // 64
  int* csr_src     = (int*)(bias2cat + 64);             // ETOT
  unsigned* rowptr = (unsigned*)(csr_src + (size_t)ETOT);  // N+1
  unsigned* cursor = rowptr + (N_NODES + 1);            // NREP*NB
  unsigned* bucket_base = cursor + NREP * NB;           // NB+1
  unsigned* bins   = bucket_base + NB + 1;              // NB*BCAP (~8.8 MB)

  // ---- CSR chain + prep (bin || pack fused) ----
  (void)hipMemsetAsync(cursor, 0, (size_t)NREP * NB * sizeof(unsigned), stream);
  fusedA_kernel<<<NCHB + 20, 256, 0, stream>>>(
      ei, cursor, bins, W1l, W1r, b1l, b1r, W2l, W2r, b2l, b2r, att1, att2,
      Bperm, B2perm, biascat, bias2cat, att1h, att2h);
  scan_buckets<<<1, 1024, 0, stream>>>(cursor, bucket_base, rowptr);
  // ---- scatter || gemm1 fused ----
  fusedB_kernel<<<NB + GEMM1_BLOCKS, 256, 0, stream>>>(
      bins, cursor, bucket_base, rowptr, csr_src, x, Bperm, biascat, xl1h, xr1h);

  // ---- layer 1 gather: 2 waves/node, 2 nodes/block ----
  l1_gather_kernel<<<N_NODES / 2, 256, 0, stream>>>(
      (const __half*)xl1h, (const __half*)xr1h, csr_src, rowptr, att1h, bias1, h1h);

  // ---- layer 2 + final linear ----
  gemm2_mfma<<<GEMM1_BLOCKS, 256, 0, stream>>>(h1h, B2perm, bias2cat, xl2h, xr2h);
  l2_gather_kernel<<<(N_NODES + 3) / 4, 256, 0, stream>>>(
      xl2h, xr2h, csr_src, rowptr, att2h, bias2, Wlin, blin, out);
}

// Round 14
// 235.357 us; speedup vs baseline: 1.0775x; 1.0775x over previous
//
#include <hip/hip_runtime.h>
#include <hip/hip_fp16.h>
#include <math.h>

#define N_NODES 100000
#define E_EDGES 1600000
#define ETOT (E_EDGES + N_NODES)   // 1,700,000 with self-loops
#define NEG 0.2f
#define NB 782          // buckets: 128 nodes each
#define NREP 4          // cursor/segment replication (contention control)
#define SEG 704         // per-replica capacity: mean 511.5, sigma 22.6 -> +8.5 sigma
#define BCAP (NREP * SEG)
#define CHUNK 4096
#define NCHB ((E_EDGES + CHUNK - 1) / CHUNK)  // 391 binning blocks (real edges only)
#define GEMM1_BLOCKS ((N_NODES + 63) / 64)    // 1563

typedef _Float16 half8 __attribute__((ext_vector_type(8)));
typedef _Float16 half4v __attribute__((ext_vector_type(4)));
typedef _Float16 half2v __attribute__((ext_vector_type(2)));
typedef float floatx4 __attribute__((ext_vector_type(4)));

union H8I {
  half8 v;
  _Float16 e[8];
  int i[4];
};

__device__ __forceinline__ float elu(float v) { return v > 0.f ? v : (__expf(v) - 1.f); }

// packed fp16 score: sum(att * leakyrelu(a + r)) -> float
__device__ __forceinline__ float score8(half8 a, half8 r, half8 av) {
  half8 t = a + r;
  t = __builtin_elementwise_max(t, t * (_Float16)NEG);
  half8 s8 = t * av;
  half4v s4 = __builtin_shufflevector(s8, s8, 0, 1, 2, 3) +
              __builtin_shufflevector(s8, s8, 4, 5, 6, 7);
  half2v s2 = __builtin_shufflevector(s4, s4, 0, 1) +
              __builtin_shufflevector(s4, s4, 2, 3);
  return (float)s2[0] + (float)s2[1];
}

// ===== pack: W1/W2 -> MFMA B-fragment layout, att->fp16, bias concat (tiny) =====
__global__ __launch_bounds__(256) void pack_w_kernel(
    const float* __restrict__ W1l, const float* __restrict__ W1r,
    const float* __restrict__ b1l, const float* __restrict__ b1r,
    const float* __restrict__ W2l, const float* __restrict__ W2r,
    const float* __restrict__ b2l, const float* __restrict__ b2r,
    const float* __restrict__ att1, const float* __restrict__ att2,
    _Float16* __restrict__ Bperm, _Float16* __restrict__ B2perm,
    float* __restrict__ biascat, float* __restrict__ bias2cat,
    _Float16* __restrict__ att1h, _Float16* __restrict__ att2h) {
  int t = threadIdx.x;
  int gt = blockIdx.x * 256 + t;
  int gstr = gridDim.x * 256;
  for (int e = gt; e < 4096; e += gstr) {
    int nt = e >> 8, kt = (e >> 6) & 3, lane = e & 63;
    int n = nt * 16 + (lane & 15);
    int kb = kt * 32 + (lane >> 4) * 8;
#pragma unroll
    for (int j = 0; j < 8; j++) {
      int k = kb + j;
      float val = (n < 128) ? W1l[k * 128 + n] : W1r[k * 128 + (n - 128)];
      Bperm[(size_t)e * 8 + j] = (_Float16)val;
    }
  }
  for (int e = gt; e < 1024; e += gstr) {
    int nt = e >> 8, kt = (e >> 6) & 3, lane = e & 63;
    int n = nt * 16 + (lane & 15);
    int kb = kt * 32 + (lane >> 4) * 8;
#pragma unroll
    for (int j = 0; j < 8; j++) {
      int k = kb + j;
      float val = (n < 32) ? W2l[k * 32 + n] : W2r[k * 32 + (n - 32)];
      B2perm[(size_t)e * 8 + j] = (_Float16)val;
    }
  }
  if (blockIdx.x == 0) {
    biascat[t] = (t < 128) ? b1l[t] : b1r[t - 128];
    if (t < 64) bias2cat[t] = (t < 32) ? b2l[t] : b2r[t - 32];
    if (t < 128) att1h[t] = (_Float16)att1[t];
    if (t < 32) att2h[t] = (_Float16)att2[t];
  }
}

// ===== fusedbin: block-aggregated binning (blocks 0..NCHB-1) || GEMM1 MFMA (rest) =====
// bin entry: (dst&127)<<17 | src ; replica r = blockIdx&3 -> segment r of bucket
// self-loops are NOT binned (placed directly in scatter phase)
__global__ __launch_bounds__(256) void fusedbin_kernel(
    const int* __restrict__ ei, unsigned* __restrict__ cursor,
    unsigned* __restrict__ bins,
    const float* __restrict__ x, const _Float16* __restrict__ Bperm,
    const float* __restrict__ biascat,
    __half* __restrict__ xlh, __half* __restrict__ xrh) {
  __shared__ __align__(16) char smem[64 * 256];
  int t = threadIdx.x;
  if (blockIdx.x < NCHB) {
    unsigned* cnt = (unsigned*)smem;            // NB
    unsigned* base = cnt + NB;                  // NB  (12.5 KB total, fits 16 KB)
    int rep = blockIdx.x & (NREP - 1);
    for (int b = t; b < NB; b += 256) cnt[b] = 0;
    __syncthreads();
    int e0 = blockIdx.x * CHUNK;
    int dstr[CHUNK / 256];
#pragma unroll
    for (int i = 0; i < CHUNK / 256; i++) {
      int e = e0 + i * 256 + t;
      int dst = 0;
      if (e < E_EDGES) {
        dst = ei[E_EDGES + e];
        atomicAdd(&cnt[dst >> 7], 1u);
      }
      dstr[i] = dst;
    }
    __syncthreads();
    for (int b = t; b < NB; b += 256) {
      unsigned c = cnt[b];
      base[b] = c ? atomicAdd(&cursor[rep * NB + b], c) : 0u;
      cnt[b] = 0;
    }
    __syncthreads();
#pragma unroll
    for (int i = 0; i < CHUNK / 256; i++) {
      int e = e0 + i * 256 + t;
      if (e < E_EDGES) {
        int dst = dstr[i];
        int src = ei[e];
        int b = dst >> 7;
        unsigned off = atomicAdd(&cnt[b], 1u);
        bins[(size_t)b * BCAP + rep * SEG + base[b] + off] =
            ((unsigned)(dst & 127) << 17) | (unsigned)src;
      }
    }
  } else {
    // ---- GEMM1: x[N,128]f32 (cvt in staging) @ [128,256]f16 -> xlh, xrh ----
    int base = (blockIdx.x - NCHB) * 64;
    {
      int row = t >> 2, c4 = t & 3;
      int grow = base + row;
      const float* gp = x + (size_t)grow * 128 + c4 * 32;
#pragma unroll
      for (int j = 0; j < 4; j++) {
        half8 v = {};
        if (grow < N_NODES) {
          float4 f0 = *(const float4*)(gp + j * 8);
          float4 f1 = *(const float4*)(gp + j * 8 + 4);
          v[0] = (_Float16)f0.x; v[1] = (_Float16)f0.y;
          v[2] = (_Float16)f0.z; v[3] = (_Float16)f0.w;
          v[4] = (_Float16)f1.x; v[5] = (_Float16)f1.y;
          v[6] = (_Float16)f1.z; v[7] = (_Float16)f1.w;
        }
        int off = row * 256 + ((((c4 * 4 + j) * 16)) ^ ((row & 7) << 4));
        *(half8*)(smem + off) = v;
      }
    }
    int wid = t >> 6, lane = t & 63;
    half8 bf[4][4];  // [ntl][kt]
#pragma unroll
    for (int ntl = 0; ntl < 4; ntl++)
#pragma unroll
      for (int kt = 0; kt < 4; kt++) {
        int f = (wid * 4 + ntl) * 4 + kt;
        bf[ntl][kt] = *(const half8*)(Bperm + ((size_t)f * 64 + lane) * 8);
      }
    floatx4 acc[4][4] = {};  // [mt][ntl]
    __syncthreads();
#pragma unroll
    for (int kt = 0; kt < 4; kt++) {
      half8 a[4];
#pragma unroll
      for (int mt = 0; mt < 4; mt++) {
        int row = mt * 16 + (lane & 15);
        int kchunk = kt * 4 + (lane >> 4);
        int off = row * 256 + ((kchunk * 16) ^ ((row & 7) << 4));
        a[mt] = *(const half8*)(smem + off);
      }
#pragma unroll
      for (int mt = 0; mt < 4; mt++)
#pragma unroll
        for (int ntl = 0; ntl < 4; ntl++)
          acc[mt][ntl] = __builtin_amdgcn_mfma_f32_16x16x32_f16(a[mt], bf[ntl][kt],
                                                                acc[mt][ntl], 0, 0, 0);
    }
#pragma unroll
    for (int mt = 0; mt < 4; mt++) {
#pragma unroll
      for (int i = 0; i < 4; i++) {
        int row = base + mt * 16 + (lane >> 4) * 4 + i;
        if (row >= N_NODES) continue;
#pragma unroll
        for (int ntl = 0; ntl < 4; ntl++) {
          int col = wid * 64 + ntl * 16 + (lane & 15);
          float v = acc[mt][ntl][i] + biascat[col];
          if (col < 128) xlh[(size_t)row * 128 + col] = __float2half_rn(v);
          else xrh[(size_t)row * 128 + (col - 128)] = __float2half_rn(v);
        }
      }
    }
  }
}

// ===== bucket-total scan: total[b] = sum_r cursor[r][b] + nodes_in_bucket(b) =====
__global__ __launch_bounds__(1024) void scan_buckets(const unsigned* __restrict__ cursor,
                                                     unsigned* __restrict__ bucket_base,
                                                     unsigned* __restrict__ rowptr) {
  __shared__ unsigned s[1024];
  int t = threadIdx.x;
  unsigned v = 0;
  if (t < NB) {
#pragma unroll
    for (int r = 0; r < NREP; r++) v += cursor[r * NB + t];
    int nib = N_NODES - (t << 7);
    v += (nib > 128) ? 128u : (unsigned)nib;   // self-loop slots
  }
  s[t] = v;
  __syncthreads();
  for (int off = 1; off < 1024; off <<= 1) {
    unsigned a = (t >= off) ? s[t - off] : 0u;
    __syncthreads();
    s[t] += a;
    __syncthreads();
  }
  if (t < NB) bucket_base[t] = s[t] - v;
  if (t == 0) { bucket_base[NB] = ETOT; rowptr[N_NODES] = ETOT; }
}

// ===== scatter: per-bucket local rowptr + self-loop + placement (LDS only) =====
__global__ __launch_bounds__(256) void scatter2_kernel(
    const unsigned* __restrict__ bins, const unsigned* __restrict__ cursor,
    const unsigned* __restrict__ bucket_base,
    unsigned* __restrict__ rowptr, int* __restrict__ csr_src) {
  __shared__ unsigned cnt[128];
  __shared__ unsigned pref[128];
  int b = blockIdx.x, t = threadIdx.x;
  int nib = N_NODES - (b << 7);
  if (nib > 128) nib = 128;
  unsigned bbase = bucket_base[b];
  unsigned crs[NREP];
#pragma unroll
  for (int r = 0; r < NREP; r++) crs[r] = cursor[r * NB + b];
  const unsigned* bp = bins + (size_t)b * BCAP;
  if (t < 128) cnt[t] = 0;
  __syncthreads();
#pragma unroll
  for (int r = 0; r < NREP; r++)
    for (unsigned i = t; i < crs[r]; i += 256)
      atomicAdd(&cnt[bp[r * SEG + i] >> 17], 1u);
  __syncthreads();
  if (t < 128) pref[t] = (t < nib) ? cnt[t] + 1u : 0u;
  __syncthreads();
  for (int off = 1; off < 128; off <<= 1) {
    unsigned a = (t >= off && t < 128) ? pref[t - off] : 0u;
    __syncthreads();
    if (t < 128) pref[t] += a;
    __syncthreads();
  }
  if (t < 128) {
    unsigned tot = (t < nib) ? cnt[t] + 1u : 0u;
    unsigned excl = pref[t] - tot;
    pref[t] = excl;
    if (t < nib) {
      int n = (b << 7) + t;
      rowptr[n] = bbase + excl;
      csr_src[bbase + excl] = n;   // self-loop at slot 0
    }
    cnt[t] = 0;
  }
  __syncthreads();
#pragma unroll
  for (int r = 0; r < NREP; r++)
    for (unsigned i = t; i < crs[r]; i += 256) {
      unsigned en = bp[r * SEG + i];
      int j = (int)(en >> 17);
      unsigned off = atomicAdd(&cnt[j], 1u);
      csr_src[bbase + pref[j] + 1u + off] = (int)(en & 0x1FFFFu);
    }
}

// ====== GEMM2 (MFMA): h1[N,128]f16 @ [128,64]f16 -> xl2h, xr2h (fp16) ======
__global__ __launch_bounds__(256) void gemm2_mfma(
    const __half* __restrict__ h1h, const _Float16* __restrict__ B2perm,
    const float* __restrict__ bias2cat,
    __half* __restrict__ xl2h, __half* __restrict__ xr2h) {
  __shared__ __align__(16) char smem[64 * 256];
  int t = threadIdx.x;
  int base = blockIdx.x * 64;
  {
    int row = t >> 2, c4 = t & 3;
    int grow = base + row;
    const char* gp = (const char*)(h1h + (size_t)grow * 128 + c4 * 32);
#pragma unroll
    for (int j = 0; j < 4; j++) {
      half8 v = {};
      if (grow < N_NODES) v = *(const half8*)(gp + j * 16);
      int off = row * 256 + ((((c4 * 4 + j) * 16)) ^ ((row & 7) << 4));
      *(half8*)(smem + off) = v;
    }
  }
  int wid = t >> 6, lane = t & 63;
  half8 bf[4];  // [kt]
#pragma unroll
  for (int kt = 0; kt < 4; kt++) {
    int f = wid * 4 + kt;
    bf[kt] = *(const half8*)(B2perm + ((size_t)f * 64 + lane) * 8);
  }
  floatx4 acc[4] = {};
  __syncthreads();
#pragma unroll
  for (int kt = 0; kt < 4; kt++) {
    half8 a[4];
#pragma unroll
    for (int mt = 0; mt < 4; mt++) {
      int row = mt * 16 + (lane & 15);
      int kchunk = kt * 4 + (lane >> 4);
      int off = row * 256 + ((kchunk * 16) ^ ((row & 7) << 4));
      a[mt] = *(const half8*)(smem + off);
    }
#pragma unroll
    for (int mt = 0; mt < 4; mt++)
      acc[mt] = __builtin_amdgcn_mfma_f32_16x16x32_f16(a[mt], bf[kt], acc[mt], 0, 0, 0);
  }
  int col = wid * 16 + (lane & 15);
  float bv = bias2cat[col];
#pragma unroll
  for (int mt = 0; mt < 4; mt++) {
#pragma unroll
    for (int i = 0; i < 4; i++) {
      int row = base + mt * 16 + (lane >> 4) * 4 + i;
      if (row >= N_NODES) continue;
      float v = acc[mt][i] + bv;
      if (col < 32) xl2h[(size_t)row * 32 + col] = __float2half_rn(v);
      else xr2h[(size_t)row * 32 + (col - 32)] = __float2half_rn(v);
    }
  }
}

// ===== L1 fused gather (R12-verified): 1 wave/node; 4 edges/slot-group; 2x ILP =====
// shifted no-max softmax: p = exp(v-4) cancels in the ratio; fp16 packed acc
__global__ __launch_bounds__(256) void l1_gather_kernel(
    const __half* __restrict__ xlh, const __half* __restrict__ xrh,
    const int* __restrict__ csr_src, const unsigned* __restrict__ rowptr,
    const _Float16* __restrict__ att1h, const float* __restrict__ bias,
    __half* __restrict__ h1h) {
  int wid = threadIdx.x >> 6;
  int lane = threadIdx.x & 63;
  int n = blockIdx.x * 4 + wid;
  if (n >= N_NODES) return;
  int g = lane >> 4;        // edge slot 0..3
  int q = lane & 15;        // channel slice: ch q*8..q*8+7 (head = q>>2)
  int c0 = q * 8;
  half8 rv = *(const half8*)(xrh + (size_t)n * 128 + c0);
  half8 av = *(const half8*)(att1h + c0);
  unsigned beg = rowptr[n], end = rowptr[n + 1];
  unsigned deg = end - beg;
  unsigned niter = deg >> 2, rem = deg & 3;
  float d0 = 0.f, d1 = 0.f;
  H8I acc0, acc1;
  acc0.v = (half8){};
  acc1.v = (half8){};
  unsigned e = beg + g;
  unsigned i = 0;
  for (; i + 2 <= niter; i += 2, e += 8) {
    int s0 = csr_src[e];
    int s1 = csr_src[e + 4];
    H8I a0, a1;
    a0.v = *(const half8*)(xlh + (size_t)s0 * 128 + c0);
    a1.v = *(const half8*)(xlh + (size_t)s1 * 128 + c0);
    float v0 = score8(a0.v, rv, av);
    float v1 = score8(a1.v, rv, av);
    v0 += __shfl_xor(v0, 1);  v1 += __shfl_xor(v1, 1);
    v0 += __shfl_xor(v0, 2);  v1 += __shfl_xor(v1, 2);
    float p0 = __expf(v0 - 4.f);
    float p1 = __expf(v1 - 4.f);
    d0 += p0; d1 += p1;
    _Float16 ph0 = (_Float16)p0, ph1 = (_Float16)p1;
    half8 p80 = {ph0, ph0, ph0, ph0, ph0, ph0, ph0, ph0};
    half8 p81 = {ph1, ph1, ph1, ph1, ph1, ph1, ph1, ph1};
    acc0.v = p80 * a0.v + acc0.v;
    acc1.v = p81 * a1.v + acc1.v;
  }
  if (i < niter) {  // odd leftover full iteration
    int s0 = csr_src[e];
    H8I a0;
    a0.v = *(const half8*)(xlh + (size_t)s0 * 128 + c0);
    float v0 = score8(a0.v, rv, av);
    v0 += __shfl_xor(v0, 1);
    v0 += __shfl_xor(v0, 2);
    float p0 = __expf(v0 - 4.f);
    d0 += p0;
    _Float16 ph0 = (_Float16)p0;
    half8 p80 = {ph0, ph0, ph0, ph0, ph0, ph0, ph0, ph0};
    acc0.v = p80 * a0.v + acc0.v;
    e += 4;
  }
  if (rem) {
    bool valid = (unsigned)g < rem;
    int s0 = csr_src[valid ? e : beg];
    H8I a0;
    a0.v = *(const half8*)(xlh + (size_t)s0 * 128 + c0);
    float v0 = score8(a0.v, rv, av);
    v0 += __shfl_xor(v0, 1);
    v0 += __shfl_xor(v0, 2);
    float p0 = valid ? __expf(v0 - 4.f) : 0.f;
    d0 += p0;
    _Float16 ph0 = (_Float16)p0;
    half8 p80 = {ph0, ph0, ph0, ph0, ph0, ph0, ph0, ph0};
    acc0.v = p80 * a0.v + acc0.v;
  }
  // merge the two ILP states, then the 4 edge-slot groups
  float d = d0 + d1;
  H8I acc;
  acc.v = acc0.v + acc1.v;
#pragma unroll
  for (int msk = 16; msk <= 32; msk <<= 1) {
    d += __shfl_xor(d, msk);
    H8I o;
#pragma unroll
    for (int k = 0; k < 4; k++) o.i[k] = __shfl_xor(acc.i[k], msk);
    acc.v = acc.v + o.v;
  }
  if (g == 0) {
    float inv = 1.f / d;
    H8I res;
#pragma unroll
    for (int j = 0; j < 8; j++)
      res.e[j] = (_Float16)elu((float)acc.e[j] * inv + bias[c0 + j]);
    *(half8*)(h1h + (size_t)n * 128 + c0) = res.v;
  }
}

// ===== L2 fused gather + final linear (R12-verified): 1 wave/node; 16 edges/iter =====
__global__ __launch_bounds__(256) void l2_gather_kernel(
    const __half* __restrict__ xl2h, const __half* __restrict__ xr2h,
    const int* __restrict__ csr_src, const unsigned* __restrict__ rowptr,
    const _Float16* __restrict__ att2h, const float* __restrict__ bias,
    const float* __restrict__ Wlin, const float* __restrict__ blin,
    float* __restrict__ out) {
  int wid = threadIdx.x >> 6;
  int lane = threadIdx.x & 63;
  int n = blockIdx.x * 4 + wid;
  if (n >= N_NODES) return;
  int g = lane >> 2;        // edge slot 0..15
  int q = lane & 3;         // channel slice: ch q*8..q*8+7
  int c0 = q * 8;
  half8 rv = *(const half8*)(xr2h + (size_t)n * 32 + c0);
  half8 av = *(const half8*)(att2h + c0);
  unsigned beg = rowptr[n], end = rowptr[n + 1];
  unsigned deg = end - beg;
  unsigned nfull = deg >> 4, rem = deg & 15;
  float d = 0.f;
  H8I acc;
  acc.v = (half8){};
  unsigned e = beg + g;
  for (unsigned i = 0; i < nfull; i++, e += 16) {
    int s = csr_src[e];
    H8I a;
    a.v = *(const half8*)(xl2h + (size_t)s * 32 + c0);
    float v = score8(a.v, rv, av);
    v += __shfl_xor(v, 1);
    v += __shfl_xor(v, 2);   // score over 4 lanes = 32 ch
    float p = __expf(v - 4.f);
    d += p;
    _Float16 ph = (_Float16)p;
    half8 p8 = {ph, ph, ph, ph, ph, ph, ph, ph};
    acc.v = p8 * a.v + acc.v;
  }
  if (rem) {
    bool valid = (unsigned)g < rem;
    int s = csr_src[valid ? e : beg];
    H8I a;
    a.v = *(const half8*)(xl2h + (size_t)s * 32 + c0);
    float v = score8(a.v, rv, av);
    v += __shfl_xor(v, 1);
    v += __shfl_xor(v, 2);
    float p = valid ? __expf(v - 4.f) : 0.f;
    d += p;
    _Float16 ph = (_Float16)p;
    half8 p8 = {ph, ph, ph, ph, ph, ph, ph, ph};
    acc.v = p8 * a.v + acc.v;
  }
  // merge the 16 edge-slot groups (lane distance 4, 8, 16, 32)
#pragma unroll
  for (int msk = 4; msk <= 32; msk <<= 1) {
    d += __shfl_xor(d, msk);
    H8I o;
#pragma unroll
    for (int k = 0; k < 4; k++) o.i[k] = __shfl_xor(acc.i[k], msk);
    acc.v = acc.v + o.v;
  }
  float inv = 1.f / d;
  float o0 = 0.f, o1 = 0.f;
#pragma unroll
  for (int j = 0; j < 8; j++) {
    float v = elu((float)acc.e[j] * inv + bias[c0 + j]);
    o0 = fmaf(v, Wlin[(c0 + j) * 2 + 0], o0);
    o1 = fmaf(v, Wlin[(c0 + j) * 2 + 1], o1);
  }
  o0 += __shfl_xor(o0, 1); o1 += __shfl_xor(o1, 1);
  o0 += __shfl_xor(o0, 2); o1 += __shfl_xor(o1, 2);
  if (lane == 0) {
    out[(size_t)n * 2 + 0] = o0 + blin[0];
    out[(size_t)n * 2 + 1] = o1 + blin[1];
  }
}

extern "C" void kernel_launch(void* const* d_in, const int* in_sizes, int n_in,
                              void* d_out, int out_size, void* d_ws, size_t ws_size,
                              hipStream_t stream) {
  const float* x     = (const float*)d_in[0];
  const int*   ei    = (const int*)d_in[1];
  const float* W1l   = (const float*)d_in[2];
  const float* b1l   = (const float*)d_in[3];
  const float* W1r   = (const float*)d_in[4];
  const float* b1r   = (const float*)d_in[5];
  const float* att1  = (const float*)d_in[6];
  const float* bias1 = (const float*)d_in[7];
  const float* W2l   = (const float*)d_in[8];
  const float* b2l   = (const float*)d_in[9];
  const float* W2r   = (const float*)d_in[10];
  const float* b2r   = (const float*)d_in[11];
  const float* att2  = (const float*)d_in[12];
  const float* bias2 = (const float*)d_in[13];
  const float* Wlin  = (const float*)d_in[14];
  const float* blin  = (const float*)d_in[15];
  float* out = (float*)d_out;

  // workspace layout
  __half* xl1h  = (__half*)d_ws;                        // N*128
  __half* xr1h  = xl1h + (size_t)N_NODES * 128;         // N*128
  __half* h1h   = xr1h + (size_t)N_NODES * 128;         // N*128
  __half* xl2h  = h1h + (size_t)N_NODES * 128;          // N*32
  __half* xr2h  = xl2h + (size_t)N_NODES * 32;          // N*32
  _Float16* Bperm  = (_Float16*)(xr2h + (size_t)N_NODES * 32);  // 32768
  _Float16* B2perm = Bperm + 32768;                     // 8192
  _Float16* att1h  = B2perm + 8192;                     // 128
  _Float16* att2h  = att1h + 128;                       // 32
  float* biascat   = (float*)(att2h + 32);              // 256
  float* bias2cat  = biascat + 256;                     // 64
  int* csr_src     = (int*)(bias2cat + 64);             // ETOT
  unsigned* rowptr = (unsigned*)(csr_src + (size_t)ETOT);  // N+1
  unsigned* cursor = rowptr + (N_NODES + 1);            // NREP*NB
  unsigned* bucket_base = cursor + NREP * NB;           // NB+1
  unsigned* bins   = bucket_base + NB + 1;              // NB*BCAP (~8.8 MB)

  // ---- prep + CSR chain; gemm1 overlaps the bin phase ----
  (void)hipMemsetAsync(cursor, 0, (size_t)NREP * NB * sizeof(unsigned), stream);
  pack_w_kernel<<<4, 256, 0, stream>>>(W1l, W1r, b1l, b1r, W2l, W2r, b2l, b2r,
                                       att1, att2, Bperm, B2perm, biascat, bias2cat,
                                       att1h, att2h);
  fusedbin_kernel<<<NCHB + GEMM1_BLOCKS, 256, 0, stream>>>(
      ei, cursor, bins, x, Bperm, biascat, xl1h, xr1h);
  scan_buckets<<<1, 1024, 0, stream>>>(cursor, bucket_base, rowptr);
  scatter2_kernel<<<NB, 256, 0, stream>>>(bins, cursor, bucket_base, rowptr, csr_src);

  // ---- layer 1 gather ----
  l1_gather_kernel<<<(N_NODES + 3) / 4, 256, 0, stream>>>(
      (const __half*)xl1h, (const __half*)xr1h, csr_src, rowptr, att1h, bias1, h1h);

  // ---- layer 2 + final linear ----
  gemm2_mfma<<<GEMM1_BLOCKS, 256, 0, stream>>>(h1h, B2perm, bias2cat, xl2h, xr2h);
  l2_gather_kernel<<<(N_NODES + 3) / 4, 256, 0, stream>>>(
      xl2h, xr2h, csr_src, rowptr, att2h, bias2, Wlin, blin, out);
}

// Round 15
// 230.376 us; speedup vs baseline: 1.1008x; 1.0216x over previous
//
#include <hip/hip_runtime.h>
#include <hip/hip_fp16.h>
#include <math.h>

#define N_NODES 100000
#define E_EDGES 1600000
#define ETOT (E_EDGES + N_NODES)   // 1,700,000 with self-loops
#define NEG 0.2f
#define NB 782          // buckets: 128 nodes each
#define NREP 4          // cursor/segment replication (contention control)
#define SEG 704         // per-replica capacity: mean 511.5, sigma 22.6 -> +8.5 sigma
#define BCAP (NREP * SEG)
#define CHUNK 4096
#define NCHB ((E_EDGES + CHUNK - 1) / CHUNK)  // 391 binning blocks (real edges only)
#define GEMM1_BLOCKS ((N_NODES + 63) / 64)    // 1563

typedef _Float16 half8 __attribute__((ext_vector_type(8)));
typedef _Float16 half4v __attribute__((ext_vector_type(4)));
typedef _Float16 half2v __attribute__((ext_vector_type(2)));
typedef float floatx4 __attribute__((ext_vector_type(4)));

union H8I {
  half8 v;
  _Float16 e[8];
  int i[4];
};

__device__ __forceinline__ float elu(float v) { return v > 0.f ? v : (__expf(v) - 1.f); }

// packed fp16 score: sum(att * leakyrelu(a + r)) -> float
__device__ __forceinline__ float score8(half8 a, half8 r, half8 av) {
  half8 t = a + r;
  t = __builtin_elementwise_max(t, t * (_Float16)NEG);
  half8 s8 = t * av;
  half4v s4 = __builtin_shufflevector(s8, s8, 0, 1, 2, 3) +
              __builtin_shufflevector(s8, s8, 4, 5, 6, 7);
  half2v s2 = __builtin_shufflevector(s4, s4, 0, 1) +
              __builtin_shufflevector(s4, s4, 2, 3);
  return (float)s2[0] + (float)s2[1];
}

// ===== fusedA: block-aggregated binning of REAL edges (blocks 0..NCHB-1) || pack =====
// bin entry: (dst&127)<<17 | src ; replica r = blockIdx&3 -> segment r of bucket
// self-loops are NOT binned (placed directly in scatter phase)
__global__ __launch_bounds__(256) void fusedA_kernel(
    const int* __restrict__ ei, unsigned* __restrict__ cursor,
    unsigned* __restrict__ bins,
    const float* __restrict__ W1l, const float* __restrict__ W1r,
    const float* __restrict__ b1l, const float* __restrict__ b1r,
    const float* __restrict__ W2l, const float* __restrict__ W2r,
    const float* __restrict__ b2l, const float* __restrict__ b2r,
    const float* __restrict__ att1, const float* __restrict__ att2,
    _Float16* __restrict__ Bperm, _Float16* __restrict__ B2perm,
    float* __restrict__ biascat, float* __restrict__ bias2cat,
    _Float16* __restrict__ att1h, _Float16* __restrict__ att2h) {
  int t = threadIdx.x;
  if (blockIdx.x < NCHB) {
    __shared__ unsigned cnt[NB];
    __shared__ unsigned base[NB];
    int rep = blockIdx.x & (NREP - 1);
    for (int b = t; b < NB; b += 256) cnt[b] = 0;
    __syncthreads();
    int e0 = blockIdx.x * CHUNK;
    int dstr[CHUNK / 256];
#pragma unroll
    for (int i = 0; i < CHUNK / 256; i++) {
      int e = e0 + i * 256 + t;
      int dst = 0;
      if (e < E_EDGES) {
        dst = ei[E_EDGES + e];
        atomicAdd(&cnt[dst >> 7], 1u);
      }
      dstr[i] = dst;
    }
    __syncthreads();
    for (int b = t; b < NB; b += 256) {
      unsigned c = cnt[b];
      base[b] = c ? atomicAdd(&cursor[rep * NB + b], c) : 0u;
      cnt[b] = 0;
    }
    __syncthreads();
#pragma unroll
    for (int i = 0; i < CHUNK / 256; i++) {
      int e = e0 + i * 256 + t;
      if (e < E_EDGES) {
        int dst = dstr[i];
        int src = ei[e];
        int b = dst >> 7;
        unsigned off = atomicAdd(&cnt[b], 1u);
        bins[(size_t)b * BCAP + rep * SEG + base[b] + off] =
            ((unsigned)(dst & 127) << 17) | (unsigned)src;
      }
    }
  } else {
    int pb = blockIdx.x - NCHB;
    int gt = pb * 256 + t;
    int gstr = 20 * 256;
    for (int e = gt; e < 4096; e += gstr) {
      int nt = e >> 8, kt = (e >> 6) & 3, lane = e & 63;
      int n = nt * 16 + (lane & 15);
      int kb = kt * 32 + (lane >> 4) * 8;
#pragma unroll
      for (int j = 0; j < 8; j++) {
        int k = kb + j;
        float val = (n < 128) ? W1l[k * 128 + n] : W1r[k * 128 + (n - 128)];
        Bperm[(size_t)e * 8 + j] = (_Float16)val;
      }
    }
    for (int e = gt; e < 1024; e += gstr) {
      int nt = e >> 8, kt = (e >> 6) & 3, lane = e & 63;
      int n = nt * 16 + (lane & 15);
      int kb = kt * 32 + (lane >> 4) * 8;
#pragma unroll
      for (int j = 0; j < 8; j++) {
        int k = kb + j;
        float val = (n < 32) ? W2l[k * 32 + n] : W2r[k * 32 + (n - 32)];
        B2perm[(size_t)e * 8 + j] = (_Float16)val;
      }
    }
    if (pb == 0) {
      biascat[t] = (t < 128) ? b1l[t] : b1r[t - 128];
      if (t < 64) bias2cat[t] = (t < 32) ? b2l[t] : b2r[t - 32];
      if (t < 128) att1h[t] = (_Float16)att1[t];
      if (t < 32) att2h[t] = (_Float16)att2[t];
    }
  }
}

// ===== bucket-total scan: total[b] = sum_r cursor[r][b] + nodes_in_bucket(b) =====
__global__ __launch_bounds__(1024) void scan_buckets(const unsigned* __restrict__ cursor,
                                                     unsigned* __restrict__ bucket_base,
                                                     unsigned* __restrict__ rowptr) {
  __shared__ unsigned s[1024];
  int t = threadIdx.x;
  unsigned v = 0;
  if (t < NB) {
#pragma unroll
    for (int r = 0; r < NREP; r++) v += cursor[r * NB + t];
    int nib = N_NODES - (t << 7);
    v += (nib > 128) ? 128u : (unsigned)nib;   // self-loop slots
  }
  s[t] = v;
  __syncthreads();
  for (int off = 1; off < 1024; off <<= 1) {
    unsigned a = (t >= off) ? s[t - off] : 0u;
    __syncthreads();
    s[t] += a;
    __syncthreads();
  }
  if (t < NB) bucket_base[t] = s[t] - v;
  if (t == 0) { bucket_base[NB] = ETOT; rowptr[N_NODES] = ETOT; }
}

// ===== fusedB: per-bucket scatter + self-loop placement (blocks 0..NB-1) || GEMM1 =====
__global__ __launch_bounds__(256) void fusedB_kernel(
    const unsigned* __restrict__ bins, const unsigned* __restrict__ cursor,
    const unsigned* __restrict__ bucket_base,
    unsigned* __restrict__ rowptr, int* __restrict__ csr_src,
    const float* __restrict__ x, const _Float16* __restrict__ Bperm,
    const float* __restrict__ biascat,
    __half* __restrict__ xlh, __half* __restrict__ xrh) {
  __shared__ __align__(16) char smem[64 * 256];
  int t = threadIdx.x;
  if (blockIdx.x < NB) {
    unsigned* cnt = (unsigned*)smem;
    unsigned* pref = cnt + 128;
    int b = blockIdx.x;
    int nib = N_NODES - (b << 7);
    if (nib > 128) nib = 128;
    unsigned bbase = bucket_base[b];
    unsigned crs[NREP];
#pragma unroll
    for (int r = 0; r < NREP; r++) crs[r] = cursor[r * NB + b];
    const unsigned* bp = bins + (size_t)b * BCAP;
    if (t < 128) cnt[t] = 0;
    __syncthreads();
#pragma unroll
    for (int r = 0; r < NREP; r++)
      for (unsigned i = t; i < crs[r]; i += 256)
        atomicAdd(&cnt[bp[r * SEG + i] >> 17], 1u);
    __syncthreads();
    if (t < 128) pref[t] = (t < nib) ? cnt[t] + 1u : 0u;
    __syncthreads();
    for (int off = 1; off < 128; off <<= 1) {
      unsigned a = (t >= off && t < 128) ? pref[t - off] : 0u;
      __syncthreads();
      if (t < 128) pref[t] += a;
      __syncthreads();
    }
    if (t < 128) {
      unsigned tot = (t < nib) ? cnt[t] + 1u : 0u;
      unsigned excl = pref[t] - tot;
      pref[t] = excl;
      if (t < nib) {
        int n = (b << 7) + t;
        rowptr[n] = bbase + excl;
        csr_src[bbase + excl] = n;   // self-loop at slot 0
      }
      cnt[t] = 0;
    }
    __syncthreads();
#pragma unroll
    for (int r = 0; r < NREP; r++)
      for (unsigned i = t; i < crs[r]; i += 256) {
        unsigned en = bp[r * SEG + i];
        int j = (int)(en >> 17);
        unsigned off = atomicAdd(&cnt[j], 1u);
        csr_src[bbase + pref[j] + 1u + off] = (int)(en & 0x1FFFFu);
      }
  } else {
    // ---- GEMM1: x[N,128]f32 (cvt in staging) @ [128,256]f16 -> xlh, xrh ----
    int base = (blockIdx.x - NB) * 64;
    {
      int row = t >> 2, c4 = t & 3;
      int grow = base + row;
      const float* gp = x + (size_t)grow * 128 + c4 * 32;
#pragma unroll
      for (int j = 0; j < 4; j++) {
        half8 v = {};
        if (grow < N_NODES) {
          float4 f0 = *(const float4*)(gp + j * 8);
          float4 f1 = *(const float4*)(gp + j * 8 + 4);
          v[0] = (_Float16)f0.x; v[1] = (_Float16)f0.y;
          v[2] = (_Float16)f0.z; v[3] = (_Float16)f0.w;
          v[4] = (_Float16)f1.x; v[5] = (_Float16)f1.y;
          v[6] = (_Float16)f1.z; v[7] = (_Float16)f1.w;
        }
        int off = row * 256 + ((((c4 * 4 + j) * 16)) ^ ((row & 7) << 4));
        *(half8*)(smem + off) = v;
      }
    }
    int wid = t >> 6, lane = t & 63;
    half8 bf[4][4];  // [ntl][kt]
#pragma unroll
    for (int ntl = 0; ntl < 4; ntl++)
#pragma unroll
      for (int kt = 0; kt < 4; kt++) {
        int f = (wid * 4 + ntl) * 4 + kt;
        bf[ntl][kt] = *(const half8*)(Bperm + ((size_t)f * 64 + lane) * 8);
      }
    floatx4 acc[4][4] = {};  // [mt][ntl]
    __syncthreads();
#pragma unroll
    for (int kt = 0; kt < 4; kt++) {
      half8 a[4];
#pragma unroll
      for (int mt = 0; mt < 4; mt++) {
        int row = mt * 16 + (lane & 15);
        int kchunk = kt * 4 + (lane >> 4);
        int off = row * 256 + ((kchunk * 16) ^ ((row & 7) << 4));
        a[mt] = *(const half8*)(smem + off);
      }
#pragma unroll
      for (int mt = 0; mt < 4; mt++)
#pragma unroll
        for (int ntl = 0; ntl < 4; ntl++)
          acc[mt][ntl] = __builtin_amdgcn_mfma_f32_16x16x32_f16(a[mt], bf[ntl][kt],
                                                                acc[mt][ntl], 0, 0, 0);
    }
#pragma unroll
    for (int mt = 0; mt < 4; mt++) {
#pragma unroll
      for (int i = 0; i < 4; i++) {
        int row = base + mt * 16 + (lane >> 4) * 4 + i;
        if (row >= N_NODES) continue;
#pragma unroll
        for (int ntl = 0; ntl < 4; ntl++) {
          int col = wid * 64 + ntl * 16 + (lane & 15);
          float v = acc[mt][ntl][i] + biascat[col];
          if (col < 128) xlh[(size_t)row * 128 + col] = __float2half_rn(v);
          else xrh[(size_t)row * 128 + (col - 128)] = __float2half_rn(v);
        }
      }
    }
  }
}

// ====== GEMM2 (MFMA): h1[N,128]f16 @ [128,64]f16 -> xl2h, xr2h (fp16) ======
__global__ __launch_bounds__(256) void gemm2_mfma(
    const __half* __restrict__ h1h, const _Float16* __restrict__ B2perm,
    const float* __restrict__ bias2cat,
    __half* __restrict__ xl2h, __half* __restrict__ xr2h) {
  __shared__ __align__(16) char smem[64 * 256];
  int t = threadIdx.x;
  int base = blockIdx.x * 64;
  {
    int row = t >> 2, c4 = t & 3;
    int grow = base + row;
    const char* gp = (const char*)(h1h + (size_t)grow * 128 + c4 * 32);
#pragma unroll
    for (int j = 0; j < 4; j++) {
      half8 v = {};
      if (grow < N_NODES) v = *(const half8*)(gp + j * 16);
      int off = row * 256 + ((((c4 * 4 + j) * 16)) ^ ((row & 7) << 4));
      *(half8*)(smem + off) = v;
    }
  }
  int wid = t >> 6, lane = t & 63;
  half8 bf[4];  // [kt]
#pragma unroll
  for (int kt = 0; kt < 4; kt++) {
    int f = wid * 4 + kt;
    bf[kt] = *(const half8*)(B2perm + ((size_t)f * 64 + lane) * 8);
  }
  floatx4 acc[4] = {};
  __syncthreads();
#pragma unroll
  for (int kt = 0; kt < 4; kt++) {
    half8 a[4];
#pragma unroll
    for (int mt = 0; mt < 4; mt++) {
      int row = mt * 16 + (lane & 15);
      int kchunk = kt * 4 + (lane >> 4);
      int off = row * 256 + ((kchunk * 16) ^ ((row & 7) << 4));
      a[mt] = *(const half8*)(smem + off);
    }
#pragma unroll
    for (int mt = 0; mt < 4; mt++)
      acc[mt] = __builtin_amdgcn_mfma_f32_16x16x32_f16(a[mt], bf[kt], acc[mt], 0, 0, 0);
  }
  int col = wid * 16 + (lane & 15);
  float bv = bias2cat[col];
#pragma unroll
  for (int mt = 0; mt < 4; mt++) {
#pragma unroll
    for (int i = 0; i < 4; i++) {
      int row = base + mt * 16 + (lane >> 4) * 4 + i;
      if (row >= N_NODES) continue;
      float v = acc[mt][i] + bv;
      if (col < 32) xl2h[(size_t)row * 32 + col] = __float2half_rn(v);
      else xr2h[(size_t)row * 32 + (col - 32)] = __float2half_rn(v);
    }
  }
}

// ===== L1 fused gather: 1 wave/node; 4 edges/slot-group; 4x ILP =====
// shifted no-max softmax: p = exp(v-4) cancels in the ratio; fp16 packed acc
__global__ __launch_bounds__(256) void l1_gather_kernel(
    const __half* __restrict__ xlh, const __half* __restrict__ xrh,
    const int* __restrict__ csr_src, const unsigned* __restrict__ rowptr,
    const _Float16* __restrict__ att1h, const float* __restrict__ bias,
    __half* __restrict__ h1h) {
  int wid = threadIdx.x >> 6;
  int lane = threadIdx.x & 63;
  int n = blockIdx.x * 4 + wid;
  if (n >= N_NODES) return;
  int g = lane >> 4;        // edge slot 0..3
  int q = lane & 15;        // channel slice: ch q*8..q*8+7 (head = q>>2)
  int c0 = q * 8;
  half8 rv = *(const half8*)(xrh + (size_t)n * 128 + c0);
  half8 av = *(const half8*)(att1h + c0);
  unsigned beg = rowptr[n], end = rowptr[n + 1];
  unsigned deg = end - beg;
  unsigned niter = deg >> 2, rem = deg & 3;
  float d0 = 0.f, d1 = 0.f, d2 = 0.f, d3 = 0.f;
  H8I acc0, acc1, acc2, acc3;
  acc0.v = (half8){};
  acc1.v = (half8){};
  acc2.v = (half8){};
  acc3.v = (half8){};
  unsigned e = beg + g;
  unsigned i = 0;
  // 4 independent gather/score/acc chains (latency hiding)
  for (; i + 4 <= niter; i += 4, e += 16) {
    int s0 = csr_src[e];
    int s1 = csr_src[e + 4];
    int s2 = csr_src[e + 8];
    int s3 = csr_src[e + 12];
    H8I a0, a1, a2, a3;
    a0.v = *(const half8*)(xlh + (size_t)s0 * 128 + c0);
    a1.v = *(const half8*)(xlh + (size_t)s1 * 128 + c0);
    a2.v = *(const half8*)(xlh + (size_t)s2 * 128 + c0);
    a3.v = *(const half8*)(xlh + (size_t)s3 * 128 + c0);
    float v0 = score8(a0.v, rv, av);
    float v1 = score8(a1.v, rv, av);
    float v2 = score8(a2.v, rv, av);
    float v3 = score8(a3.v, rv, av);
    v0 += __shfl_xor(v0, 1);  v1 += __shfl_xor(v1, 1);
    v2 += __shfl_xor(v2, 1);  v3 += __shfl_xor(v3, 1);
    v0 += __shfl_xor(v0, 2);  v1 += __shfl_xor(v1, 2);
    v2 += __shfl_xor(v2, 2);  v3 += __shfl_xor(v3, 2);
    float p0 = __expf(v0 - 4.f);
    float p1 = __expf(v1 - 4.f);
    float p2 = __expf(v2 - 4.f);
    float p3 = __expf(v3 - 4.f);
    d0 += p0; d1 += p1; d2 += p2; d3 += p3;
    _Float16 ph0 = (_Float16)p0, ph1 = (_Float16)p1;
    _Float16 ph2 = (_Float16)p2, ph3 = (_Float16)p3;
    half8 p80 = {ph0, ph0, ph0, ph0, ph0, ph0, ph0, ph0};
    half8 p81 = {ph1, ph1, ph1, ph1, ph1, ph1, ph1, ph1};
    half8 p82 = {ph2, ph2, ph2, ph2, ph2, ph2, ph2, ph2};
    half8 p83 = {ph3, ph3, ph3, ph3, ph3, ph3, ph3, ph3};
    acc0.v = p80 * a0.v + acc0.v;
    acc1.v = p81 * a1.v + acc1.v;
    acc2.v = p82 * a2.v + acc2.v;
    acc3.v = p83 * a3.v + acc3.v;
  }
  for (; i < niter; i++, e += 4) {  // leftover full iterations (0-3)
    int s0 = csr_src[e];
    H8I a0;
    a0.v = *(const half8*)(xlh + (size_t)s0 * 128 + c0);
    float v0 = score8(a0.v, rv, av);
    v0 += __shfl_xor(v0, 1);
    v0 += __shfl_xor(v0, 2);
    float p0 = __expf(v0 - 4.f);
    d0 += p0;
    _Float16 ph0 = (_Float16)p0;
    half8 p80 = {ph0, ph0, ph0, ph0, ph0, ph0, ph0, ph0};
    acc0.v = p80 * a0.v + acc0.v;
  }
  if (rem) {
    bool valid = (unsigned)g < rem;
    int s0 = csr_src[valid ? e : beg];
    H8I a0;
    a0.v = *(const half8*)(xlh + (size_t)s0 * 128 + c0);
    float v0 = score8(a0.v, rv, av);
    v0 += __shfl_xor(v0, 1);
    v0 += __shfl_xor(v0, 2);
    float p0 = valid ? __expf(v0 - 4.f) : 0.f;
    d0 += p0;
    _Float16 ph0 = (_Float16)p0;
    half8 p80 = {ph0, ph0, ph0, ph0, ph0, ph0, ph0, ph0};
    acc0.v = p80 * a0.v + acc0.v;
  }
  // merge the 4 ILP states, then the 4 edge-slot groups
  float d = (d0 + d1) + (d2 + d3);
  H8I acc;
  acc.v = (acc0.v + acc1.v) + (acc2.v + acc3.v);
#pragma unroll
  for (int msk = 16; msk <= 32; msk <<= 1) {
    d += __shfl_xor(d, msk);
    H8I o;
#pragma unroll
    for (int k = 0; k < 4; k++) o.i[k] = __shfl_xor(acc.i[k], msk);
    acc.v = acc.v + o.v;
  }
  if (g == 0) {
    float inv = 1.f / d;
    H8I res;
#pragma unroll
    for (int j = 0; j < 8; j++)
      res.e[j] = (_Float16)elu((float)acc.e[j] * inv + bias[c0 + j]);
    *(half8*)(h1h + (size_t)n * 128 + c0) = res.v;
  }
}

// ===== L2 fused gather + final linear: 1 wave/node; 16 edges/iter; loop split =====
__global__ __launch_bounds__(256) void l2_gather_kernel(
    const __half* __restrict__ xl2h, const __half* __restrict__ xr2h,
    const int* __restrict__ csr_src, const unsigned* __restrict__ rowptr,
    const _Float16* __restrict__ att2h, const float* __restrict__ bias,
    const float* __restrict__ Wlin, const float* __restrict__ blin,
    float* __restrict__ out) {
  int wid = threadIdx.x >> 6;
  int lane = threadIdx.x & 63;
  int n = blockIdx.x * 4 + wid;
  if (n >= N_NODES) return;
  int g = lane >> 2;        // edge slot 0..15
  int q = lane & 3;         // channel slice: ch q*8..q*8+7
  int c0 = q * 8;
  half8 rv = *(const half8*)(xr2h + (size_t)n * 32 + c0);
  half8 av = *(const half8*)(att2h + c0);
  unsigned beg = rowptr[n], end = rowptr[n + 1];
  unsigned deg = end - beg;
  unsigned nfull = deg >> 4, rem = deg & 15;
  float d = 0.f;
  H8I acc;
  acc.v = (half8){};
  unsigned e = beg + g;
  for (unsigned i = 0; i < nfull; i++, e += 16) {
    int s = csr_src[e];
    H8I a;
    a.v = *(const half8*)(xl2h + (size_t)s * 32 + c0);
    float v = score8(a.v, rv, av);
    v += __shfl_xor(v, 1);
    v += __shfl_xor(v, 2);   // score over 4 lanes = 32 ch
    float p = __expf(v - 4.f);
    d += p;
    _Float16 ph = (_Float16)p;
    half8 p8 = {ph, ph, ph, ph, ph, ph, ph, ph};
    acc.v = p8 * a.v + acc.v;
  }
  if (rem) {
    bool valid = (unsigned)g < rem;
    int s = csr_src[valid ? e : beg];
    H8I a;
    a.v = *(const half8*)(xl2h + (size_t)s * 32 + c0);
    float v = score8(a.v, rv, av);
    v += __shfl_xor(v, 1);
    v += __shfl_xor(v, 2);
    float p = valid ? __expf(v - 4.f) : 0.f;
    d += p;
    _Float16 ph = (_Float16)p;
    half8 p8 = {ph, ph, ph, ph, ph, ph, ph, ph};
    acc.v = p8 * a.v + acc.v;
  }
  // merge the 16 edge-slot groups (lane distance 4, 8, 16, 32)
#pragma unroll
  for (int msk = 4; msk <= 32; msk <<= 1) {
    d += __shfl_xor(d, msk);
    H8I o;
#pragma unroll
    for (int k = 0; k < 4; k++) o.i[k] = __shfl_xor(acc.i[k], msk);
    acc.v = acc.v + o.v;
  }
  float inv = 1.f / d;
  float o0 = 0.f, o1 = 0.f;
#pragma unroll
  for (int j = 0; j < 8; j++) {
    float v = elu((float)acc.e[j] * inv + bias[c0 + j]);
    o0 = fmaf(v, Wlin[(c0 + j) * 2 + 0], o0);
    o1 = fmaf(v, Wlin[(c0 + j) * 2 + 1], o1);
  }
  o0 += __shfl_xor(o0, 1); o1 += __shfl_xor(o1, 1);
  o0 += __shfl_xor(o0, 2); o1 += __shfl_xor(o1, 2);
  if (lane == 0) {
    out[(size_t)n * 2 + 0] = o0 + blin[0];
    out[(size_t)n * 2 + 1] = o1 + blin[1];
  }
}

extern "C" void kernel_launch(void* const* d_in, const int* in_sizes, int n_in,
                              void* d_out, int out_size, void* d_ws, size_t ws_size,
                              hipStream_t stream) {
  const float* x     = (const float*)d_in[0];
  const int*   ei    = (const int*)d_in[1];
  const float* W1l   = (const float*)d_in[2];
  const float* b1l   = (const float*)d_in[3];
  const float* W1r   = (const float*)d_in[4];
  const float* b1r   = (const float*)d_in[5];
  const float* att1  = (const float*)d_in[6];
  const float* bias1 = (const float*)d_in[7];
  const float* W2l   = (const float*)d_in[8];
  const float* b2l   = (const float*)d_in[9];
  const float* W2r   = (const float*)d_in[10];
  const float* b2r   = (const float*)d_in[11];
  const float* att2  = (const float*)d_in[12];
  const float* bias2 = (const float*)d_in[13];
  const float* Wlin  = (const float*)d_in[14];
  const float* blin  = (const float*)d_in[15];
  float* out = (float*)d_out;

  // workspace layout
  __half* xl1h  = (__half*)d_ws;                        // N*128
  __half* xr1h  = xl1h + (size_t)N_NODES * 128;         // N*128
  __half* h1h   = xr1h + (size_t)N_NODES * 128;         // N*128
  __half* xl2h  = h1h + (size_t)N_NODES * 128;          // N*32
  __half* xr2h  = xl2h + (size_t)N_NODES * 32;          // N*32
  _Float16* Bperm  = (_Float16*)(xr2h + (size_t)N_NODES * 32);  // 32768
  _Float16* B2perm = Bperm + 32768;                     // 8192
  _Float16* att1h  = B2perm + 8192;                     // 128
  _Float16* att2h  = att1h + 128;                       // 32
  float* biascat   = (float*)(att2h + 32);              // 256
  float* bias2cat  = biascat + 256;                     // 64
  int* csr_src     = (int*)(bias2cat + 64);             // ETOT
  unsigned* rowptr = (unsigned*)(csr_src + (size_t)ETOT);  // N+1
  unsigned* cursor = rowptr + (N_NODES + 1);            // NREP*NB
  unsigned* bucket_base = cursor + NREP * NB;           // NB+1
  unsigned* bins   = bucket_base + NB + 1;              // NB*BCAP (~8.8 MB)

  // ---- CSR chain + prep (bin || pack fused) ----
  (void)hipMemsetAsync(cursor, 0, (size_t)NREP * NB * sizeof(unsigned), stream);
  fusedA_kernel<<<NCHB + 20, 256, 0, stream>>>(
      ei, cursor, bins, W1l, W1r, b1l, b1r, W2l, W2r, b2l, b2r, att1, att2,
      Bperm, B2perm, biascat, bias2cat, att1h, att2h);
  scan_buckets<<<1, 1024, 0, stream>>>(cursor, bucket_base, rowptr);
  // ---- scatter || gemm1 fused ----
  fusedB_kernel<<<NB + GEMM1_BLOCKS, 256, 0, stream>>>(
      bins, cursor, bucket_base, rowptr, csr_src, x, Bperm, biascat, xl1h, xr1h);

  // ---- layer 1 gather ----
  l1_gather_kernel<<<(N_NODES + 3) / 4, 256, 0, stream>>>(
      (const __half*)xl1h, (const __half*)xr1h, csr_src, rowptr, att1h, bias1, h1h);

  // ---- layer 2 + final linear ----
  gemm2_mfma<<<GEMM1_BLOCKS, 256, 0, stream>>>(h1h, B2perm, bias2cat, xl2h, xr2h);
  l2_gather_kernel<<<(N_NODES + 3) / 4, 256, 0, stream>>>(
      xl2h, xr2h, csr_src, rowptr, att2h, bias2, Wlin, blin, out);
}

// Round 16
// 228.279 us; speedup vs baseline: 1.1109x; 1.0092x over previous
//
#include <hip/hip_runtime.h>
#include <hip/hip_fp16.h>
#include <math.h>

#define N_NODES 100000
#define E_EDGES 1600000
#define ETOT (E_EDGES + N_NODES)   // 1,700,000 with self-loops
#define NEG 0.2f
#define NB 782          // buckets: 128 nodes each
#define NREP 4          // cursor/segment replication (contention control)
#define SEG 704         // per-replica capacity: mean 511.5, sigma 22.6 -> +8.5 sigma
#define BCAP (NREP * SEG)
#define CHUNK 4096
#define NCHB ((E_EDGES + CHUNK - 1) / CHUNK)  // 391 binning blocks (real edges only)
#define GEMM1_BLOCKS ((N_NODES + 63) / 64)    // 1563

typedef _Float16 half8 __attribute__((ext_vector_type(8)));
typedef _Float16 half4v __attribute__((ext_vector_type(4)));
typedef _Float16 half2v __attribute__((ext_vector_type(2)));
typedef float floatx4 __attribute__((ext_vector_type(4)));

union H8I {
  half8 v;
  _Float16 e[8];
  int i[4];
};

__device__ __forceinline__ float elu(float v) { return v > 0.f ? v : (__expf(v) - 1.f); }

// packed fp16 score: sum(att * leakyrelu(a + r)) -> float
__device__ __forceinline__ float score8(half8 a, half8 r, half8 av) {
  half8 t = a + r;
  t = __builtin_elementwise_max(t, t * (_Float16)NEG);
  half8 s8 = t * av;
  half4v s4 = __builtin_shufflevector(s8, s8, 0, 1, 2, 3) +
              __builtin_shufflevector(s8, s8, 4, 5, 6, 7);
  half2v s2 = __builtin_shufflevector(s4, s4, 0, 1) +
              __builtin_shufflevector(s4, s4, 2, 3);
  return (float)s2[0] + (float)s2[1];
}

// ===== fusedA: block-aggregated binning of REAL edges (blocks 0..NCHB-1) || pack =====
// bin entry: (dst&127)<<17 | src ; replica r = blockIdx&3 -> segment r of bucket
// self-loops are NOT binned (placed directly in scatter phase)
__global__ __launch_bounds__(256) void fusedA_kernel(
    const int* __restrict__ ei, unsigned* __restrict__ cursor,
    unsigned* __restrict__ bins,
    const float* __restrict__ W1l, const float* __restrict__ W1r,
    const float* __restrict__ b1l, const float* __restrict__ b1r,
    const float* __restrict__ W2l, const float* __restrict__ W2r,
    const float* __restrict__ b2l, const float* __restrict__ b2r,
    const float* __restrict__ att1, const float* __restrict__ att2,
    _Float16* __restrict__ Bperm, _Float16* __restrict__ B2perm,
    float* __restrict__ biascat, float* __restrict__ bias2cat,
    _Float16* __restrict__ att1h, _Float16* __restrict__ att2h) {
  int t = threadIdx.x;
  if (blockIdx.x < NCHB) {
    __shared__ unsigned cnt[NB];
    __shared__ unsigned base[NB];
    int rep = blockIdx.x & (NREP - 1);
    for (int b = t; b < NB; b += 256) cnt[b] = 0;
    __syncthreads();
    int e0 = blockIdx.x * CHUNK;
    int dstr[CHUNK / 256];
#pragma unroll
    for (int i = 0; i < CHUNK / 256; i++) {
      int e = e0 + i * 256 + t;
      int dst = 0;
      if (e < E_EDGES) {
        dst = ei[E_EDGES + e];
        atomicAdd(&cnt[dst >> 7], 1u);
      }
      dstr[i] = dst;
    }
    __syncthreads();
    for (int b = t; b < NB; b += 256) {
      unsigned c = cnt[b];
      base[b] = c ? atomicAdd(&cursor[rep * NB + b], c) : 0u;
      cnt[b] = 0;
    }
    __syncthreads();
#pragma unroll
    for (int i = 0; i < CHUNK / 256; i++) {
      int e = e0 + i * 256 + t;
      if (e < E_EDGES) {
        int dst = dstr[i];
        int src = ei[e];
        int b = dst >> 7;
        unsigned off = atomicAdd(&cnt[b], 1u);
        bins[(size_t)b * BCAP + rep * SEG + base[b] + off] =
            ((unsigned)(dst & 127) << 17) | (unsigned)src;
      }
    }
  } else {
    int pb = blockIdx.x - NCHB;
    int gt = pb * 256 + t;
    int gstr = 20 * 256;
    for (int e = gt; e < 4096; e += gstr) {
      int nt = e >> 8, kt = (e >> 6) & 3, lane = e & 63;
      int n = nt * 16 + (lane & 15);
      int kb = kt * 32 + (lane >> 4) * 8;
#pragma unroll
      for (int j = 0; j < 8; j++) {
        int k = kb + j;
        float val = (n < 128) ? W1l[k * 128 + n] : W1r[k * 128 + (n - 128)];
        Bperm[(size_t)e * 8 + j] = (_Float16)val;
      }
    }
    for (int e = gt; e < 1024; e += gstr) {
      int nt = e >> 8, kt = (e >> 6) & 3, lane = e & 63;
      int n = nt * 16 + (lane & 15);
      int kb = kt * 32 + (lane >> 4) * 8;
#pragma unroll
      for (int j = 0; j < 8; j++) {
        int k = kb + j;
        float val = (n < 32) ? W2l[k * 32 + n] : W2r[k * 32 + (n - 32)];
        B2perm[(size_t)e * 8 + j] = (_Float16)val;
      }
    }
    if (pb == 0) {
      biascat[t] = (t < 128) ? b1l[t] : b1r[t - 128];
      if (t < 64) bias2cat[t] = (t < 32) ? b2l[t] : b2r[t - 32];
      if (t < 128) att1h[t] = (_Float16)att1[t];
      if (t < 32) att2h[t] = (_Float16)att2[t];
    }
  }
}

// ===== bucket-total scan: total[b] = sum_r cursor[r][b] + nodes_in_bucket(b) =====
__global__ __launch_bounds__(1024) void scan_buckets(const unsigned* __restrict__ cursor,
                                                     unsigned* __restrict__ bucket_base,
                                                     unsigned* __restrict__ rowptr) {
  __shared__ unsigned s[1024];
  int t = threadIdx.x;
  unsigned v = 0;
  if (t < NB) {
#pragma unroll
    for (int r = 0; r < NREP; r++) v += cursor[r * NB + t];
    int nib = N_NODES - (t << 7);
    v += (nib > 128) ? 128u : (unsigned)nib;   // self-loop slots
  }
  s[t] = v;
  __syncthreads();
  for (int off = 1; off < 1024; off <<= 1) {
    unsigned a = (t >= off) ? s[t - off] : 0u;
    __syncthreads();
    s[t] += a;
    __syncthreads();
  }
  if (t < NB) bucket_base[t] = s[t] - v;
  if (t == 0) { bucket_base[NB] = ETOT; rowptr[N_NODES] = ETOT; }
}

// ===== fusedB: per-bucket scatter + self-loop placement (blocks 0..NB-1) || GEMM1 =====
__global__ __launch_bounds__(256) void fusedB_kernel(
    const unsigned* __restrict__ bins, const unsigned* __restrict__ cursor,
    const unsigned* __restrict__ bucket_base,
    unsigned* __restrict__ rowptr, int* __restrict__ csr_src,
    const float* __restrict__ x, const _Float16* __restrict__ Bperm,
    const float* __restrict__ biascat,
    __half* __restrict__ xlh, __half* __restrict__ xrh) {
  __shared__ __align__(16) char smem[64 * 256];
  int t = threadIdx.x;
  if (blockIdx.x < NB) {
    unsigned* cnt = (unsigned*)smem;
    unsigned* pref = cnt + 128;
    int b = blockIdx.x;
    int nib = N_NODES - (b << 7);
    if (nib > 128) nib = 128;
    unsigned bbase = bucket_base[b];
    unsigned crs[NREP];
#pragma unroll
    for (int r = 0; r < NREP; r++) crs[r] = cursor[r * NB + b];
    const unsigned* bp = bins + (size_t)b * BCAP;
    if (t < 128) cnt[t] = 0;
    __syncthreads();
#pragma unroll
    for (int r = 0; r < NREP; r++)
      for (unsigned i = t; i < crs[r]; i += 256)
        atomicAdd(&cnt[bp[r * SEG + i] >> 17], 1u);
    __syncthreads();
    if (t < 128) pref[t] = (t < nib) ? cnt[t] + 1u : 0u;
    __syncthreads();
    for (int off = 1; off < 128; off <<= 1) {
      unsigned a = (t >= off && t < 128) ? pref[t - off] : 0u;
      __syncthreads();
      if (t < 128) pref[t] += a;
      __syncthreads();
    }
    if (t < 128) {
      unsigned tot = (t < nib) ? cnt[t] + 1u : 0u;
      unsigned excl = pref[t] - tot;
      pref[t] = excl;
      if (t < nib) {
        int n = (b << 7) + t;
        rowptr[n] = bbase + excl;
        csr_src[bbase + excl] = n;   // self-loop at slot 0
      }
      cnt[t] = 0;
    }
    __syncthreads();
#pragma unroll
    for (int r = 0; r < NREP; r++)
      for (unsigned i = t; i < crs[r]; i += 256) {
        unsigned en = bp[r * SEG + i];
        int j = (int)(en >> 17);
        unsigned off = atomicAdd(&cnt[j], 1u);
        csr_src[bbase + pref[j] + 1u + off] = (int)(en & 0x1FFFFu);
      }
  } else {
    // ---- GEMM1: x[N,128]f32 (cvt in staging) @ [128,256]f16 -> xlh, xrh ----
    int base = (blockIdx.x - NB) * 64;
    {
      int row = t >> 2, c4 = t & 3;
      int grow = base + row;
      const float* gp = x + (size_t)grow * 128 + c4 * 32;
#pragma unroll
      for (int j = 0; j < 4; j++) {
        half8 v = {};
        if (grow < N_NODES) {
          float4 f0 = *(const float4*)(gp + j * 8);
          float4 f1 = *(const float4*)(gp + j * 8 + 4);
          v[0] = (_Float16)f0.x; v[1] = (_Float16)f0.y;
          v[2] = (_Float16)f0.z; v[3] = (_Float16)f0.w;
          v[4] = (_Float16)f1.x; v[5] = (_Float16)f1.y;
          v[6] = (_Float16)f1.z; v[7] = (_Float16)f1.w;
        }
        int off = row * 256 + ((((c4 * 4 + j) * 16)) ^ ((row & 7) << 4));
        *(half8*)(smem + off) = v;
      }
    }
    int wid = t >> 6, lane = t & 63;
    half8 bf[4][4];  // [ntl][kt]
#pragma unroll
    for (int ntl = 0; ntl < 4; ntl++)
#pragma unroll
      for (int kt = 0; kt < 4; kt++) {
        int f = (wid * 4 + ntl) * 4 + kt;
        bf[ntl][kt] = *(const half8*)(Bperm + ((size_t)f * 64 + lane) * 8);
      }
    floatx4 acc[4][4] = {};  // [mt][ntl]
    __syncthreads();
#pragma unroll
    for (int kt = 0; kt < 4; kt++) {
      half8 a[4];
#pragma unroll
      for (int mt = 0; mt < 4; mt++) {
        int row = mt * 16 + (lane & 15);
        int kchunk = kt * 4 + (lane >> 4);
        int off = row * 256 + ((kchunk * 16) ^ ((row & 7) << 4));
        a[mt] = *(const half8*)(smem + off);
      }
#pragma unroll
      for (int mt = 0; mt < 4; mt++)
#pragma unroll
        for (int ntl = 0; ntl < 4; ntl++)
          acc[mt][ntl] = __builtin_amdgcn_mfma_f32_16x16x32_f16(a[mt], bf[ntl][kt],
                                                                acc[mt][ntl], 0, 0, 0);
    }
#pragma unroll
    for (int mt = 0; mt < 4; mt++) {
#pragma unroll
      for (int i = 0; i < 4; i++) {
        int row = base + mt * 16 + (lane >> 4) * 4 + i;
        if (row >= N_NODES) continue;
#pragma unroll
        for (int ntl = 0; ntl < 4; ntl++) {
          int col = wid * 64 + ntl * 16 + (lane & 15);
          float v = acc[mt][ntl][i] + biascat[col];
          if (col < 128) xlh[(size_t)row * 128 + col] = __float2half_rn(v);
          else xrh[(size_t)row * 128 + (col - 128)] = __float2half_rn(v);
        }
      }
    }
  }
}

// ====== GEMM2 (MFMA): h1[N,128]f16 @ [128,64]f16 -> xl2h, xr2h (fp16) ======
__global__ __launch_bounds__(256) void gemm2_mfma(
    const __half* __restrict__ h1h, const _Float16* __restrict__ B2perm,
    const float* __restrict__ bias2cat,
    __half* __restrict__ xl2h, __half* __restrict__ xr2h) {
  __shared__ __align__(16) char smem[64 * 256];
  int t = threadIdx.x;
  int base = blockIdx.x * 64;
  {
    int row = t >> 2, c4 = t & 3;
    int grow = base + row;
    const char* gp = (const char*)(h1h + (size_t)grow * 128 + c4 * 32);
#pragma unroll
    for (int j = 0; j < 4; j++) {
      half8 v = {};
      if (grow < N_NODES) v = *(const half8*)(gp + j * 16);
      int off = row * 256 + ((((c4 * 4 + j) * 16)) ^ ((row & 7) << 4));
      *(half8*)(smem + off) = v;
    }
  }
  int wid = t >> 6, lane = t & 63;
  half8 bf[4];  // [kt]
#pragma unroll
  for (int kt = 0; kt < 4; kt++) {
    int f = wid * 4 + kt;
    bf[kt] = *(const half8*)(B2perm + ((size_t)f * 64 + lane) * 8);
  }
  floatx4 acc[4] = {};
  __syncthreads();
#pragma unroll
  for (int kt = 0; kt < 4; kt++) {
    half8 a[4];
#pragma unroll
    for (int mt = 0; mt < 4; mt++) {
      int row = mt * 16 + (lane & 15);
      int kchunk = kt * 4 + (lane >> 4);
      int off = row * 256 + ((kchunk * 16) ^ ((row & 7) << 4));
      a[mt] = *(const half8*)(smem + off);
    }
#pragma unroll
    for (int mt = 0; mt < 4; mt++)
      acc[mt] = __builtin_amdgcn_mfma_f32_16x16x32_f16(a[mt], bf[kt], acc[mt], 0, 0, 0);
  }
  int col = wid * 16 + (lane & 15);
  float bv = bias2cat[col];
#pragma unroll
  for (int mt = 0; mt < 4; mt++) {
#pragma unroll
    for (int i = 0; i < 4; i++) {
      int row = base + mt * 16 + (lane >> 4) * 4 + i;
      if (row >= N_NODES) continue;
      float v = acc[mt][i] + bv;
      if (col < 32) xl2h[(size_t)row * 32 + col] = __float2half_rn(v);
      else xr2h[(size_t)row * 32 + (col - 32)] = __float2half_rn(v);
    }
  }
}

// ===== L1 fused gather (best-known R11/R12 form): 1 wave/node; 4 edges/slot; 2x ILP =====
// shifted no-max softmax: p = exp(v-4) cancels in the ratio; fp16 packed acc
__global__ __launch_bounds__(256) void l1_gather_kernel(
    const __half* __restrict__ xlh, const __half* __restrict__ xrh,
    const int* __restrict__ csr_src, const unsigned* __restrict__ rowptr,
    const _Float16* __restrict__ att1h, const float* __restrict__ bias,
    __half* __restrict__ h1h) {
  int wid = threadIdx.x >> 6;
  int lane = threadIdx.x & 63;
  int n = blockIdx.x * 4 + wid;
  if (n >= N_NODES) return;
  int g = lane >> 4;        // edge slot 0..3
  int q = lane & 15;        // channel slice: ch q*8..q*8+7 (head = q>>2)
  int c0 = q * 8;
  half8 rv = *(const half8*)(xrh + (size_t)n * 128 + c0);
  half8 av = *(const half8*)(att1h + c0);
  unsigned beg = rowptr[n], end = rowptr[n + 1];
  unsigned deg = end - beg;
  unsigned niter = deg >> 2, rem = deg & 3;
  float d0 = 0.f, d1 = 0.f;
  H8I acc0, acc1;
  acc0.v = (half8){};
  acc1.v = (half8){};
  unsigned e = beg + g;
  unsigned i = 0;
  for (; i + 2 <= niter; i += 2, e += 8) {
    int s0 = csr_src[e];
    int s1 = csr_src[e + 4];
    H8I a0, a1;
    a0.v = *(const half8*)(xlh + (size_t)s0 * 128 + c0);
    a1.v = *(const half8*)(xlh + (size_t)s1 * 128 + c0);
    float v0 = score8(a0.v, rv, av);
    float v1 = score8(a1.v, rv, av);
    v0 += __shfl_xor(v0, 1);  v1 += __shfl_xor(v1, 1);
    v0 += __shfl_xor(v0, 2);  v1 += __shfl_xor(v1, 2);
    float p0 = __expf(v0 - 4.f);
    float p1 = __expf(v1 - 4.f);
    d0 += p0; d1 += p1;
    _Float16 ph0 = (_Float16)p0, ph1 = (_Float16)p1;
    half8 p80 = {ph0, ph0, ph0, ph0, ph0, ph0, ph0, ph0};
    half8 p81 = {ph1, ph1, ph1, ph1, ph1, ph1, ph1, ph1};
    acc0.v = p80 * a0.v + acc0.v;
    acc1.v = p81 * a1.v + acc1.v;
  }
  if (i < niter) {  // odd leftover full iteration
    int s0 = csr_src[e];
    H8I a0;
    a0.v = *(const half8*)(xlh + (size_t)s0 * 128 + c0);
    float v0 = score8(a0.v, rv, av);
    v0 += __shfl_xor(v0, 1);
    v0 += __shfl_xor(v0, 2);
    float p0 = __expf(v0 - 4.f);
    d0 += p0;
    _Float16 ph0 = (_Float16)p0;
    half8 p80 = {ph0, ph0, ph0, ph0, ph0, ph0, ph0, ph0};
    acc0.v = p80 * a0.v + acc0.v;
    e += 4;
  }
  if (rem) {
    bool valid = (unsigned)g < rem;
    int s0 = csr_src[valid ? e : beg];
    H8I a0;
    a0.v = *(const half8*)(xlh + (size_t)s0 * 128 + c0);
    float v0 = score8(a0.v, rv, av);
    v0 += __shfl_xor(v0, 1);
    v0 += __shfl_xor(v0, 2);
    float p0 = valid ? __expf(v0 - 4.f) : 0.f;
    d0 += p0;
    _Float16 ph0 = (_Float16)p0;
    half8 p80 = {ph0, ph0, ph0, ph0, ph0, ph0, ph0, ph0};
    acc0.v = p80 * a0.v + acc0.v;
  }
  // merge the two ILP states, then the 4 edge-slot groups
  float d = d0 + d1;
  H8I acc;
  acc.v = acc0.v + acc1.v;
#pragma unroll
  for (int msk = 16; msk <= 32; msk <<= 1) {
    d += __shfl_xor(d, msk);
    H8I o;
#pragma unroll
    for (int k = 0; k < 4; k++) o.i[k] = __shfl_xor(acc.i[k], msk);
    acc.v = acc.v + o.v;
  }
  if (g == 0) {
    float inv = 1.f / d;
    H8I res;
#pragma unroll
    for (int j = 0; j < 8; j++)
      res.e[j] = (_Float16)elu((float)acc.e[j] * inv + bias[c0 + j]);
    *(half8*)(h1h + (size_t)n * 128 + c0) = res.v;
  }
}

// ===== L2 fused gather + final linear: 1 wave/node; 16 edges/iter; loop split =====
__global__ __launch_bounds__(256) void l2_gather_kernel(
    const __half* __restrict__ xl2h, const __half* __restrict__ xr2h,
    const int* __restrict__ csr_src, const unsigned* __restrict__ rowptr,
    const _Float16* __restrict__ att2h, const float* __restrict__ bias,
    const float* __restrict__ Wlin, const float* __restrict__ blin,
    float* __restrict__ out) {
  int wid = threadIdx.x >> 6;
  int lane = threadIdx.x & 63;
  int n = blockIdx.x * 4 + wid;
  if (n >= N_NODES) return;
  int g = lane >> 2;        // edge slot 0..15
  int q = lane & 3;         // channel slice: ch q*8..q*8+7
  int c0 = q * 8;
  half8 rv = *(const half8*)(xr2h + (size_t)n * 32 + c0);
  half8 av = *(const half8*)(att2h + c0);
  unsigned beg = rowptr[n], end = rowptr[n + 1];
  unsigned deg = end - beg;
  unsigned nfull = deg >> 4, rem = deg & 15;
  float d = 0.f;
  H8I acc;
  acc.v = (half8){};
  unsigned e = beg + g;
  for (unsigned i = 0; i < nfull; i++, e += 16) {
    int s = csr_src[e];
    H8I a;
    a.v = *(const half8*)(xl2h + (size_t)s * 32 + c0);
    float v = score8(a.v, rv, av);
    v += __shfl_xor(v, 1);
    v += __shfl_xor(v, 2);   // score over 4 lanes = 32 ch
    float p = __expf(v - 4.f);
    d += p;
    _Float16 ph = (_Float16)p;
    half8 p8 = {ph, ph, ph, ph, ph, ph, ph, ph};
    acc.v = p8 * a.v + acc.v;
  }
  if (rem) {
    bool valid = (unsigned)g < rem;
    int s = csr_src[valid ? e : beg];
    H8I a;
    a.v = *(const half8*)(xl2h + (size_t)s * 32 + c0);
    float v = score8(a.v, rv, av);
    v += __shfl_xor(v, 1);
    v += __shfl_xor(v, 2);
    float p = valid ? __expf(v - 4.f) : 0.f;
    d += p;
    _Float16 ph = (_Float16)p;
    half8 p8 = {ph, ph, ph, ph, ph, ph, ph, ph};
    acc.v = p8 * a.v + acc.v;
  }
  // merge the 16 edge-slot groups (lane distance 4, 8, 16, 32)
#pragma unroll
  for (int msk = 4; msk <= 32; msk <<= 1) {
    d += __shfl_xor(d, msk);
    H8I o;
#pragma unroll
    for (int k = 0; k < 4; k++) o.i[k] = __shfl_xor(acc.i[k], msk);
    acc.v = acc.v + o.v;
  }
  float inv = 1.f / d;
  float o0 = 0.f, o1 = 0.f;
#pragma unroll
  for (int j = 0; j < 8; j++) {
    float v = elu((float)acc.e[j] * inv + bias[c0 + j]);
    o0 = fmaf(v, Wlin[(c0 + j) * 2 + 0], o0);
    o1 = fmaf(v, Wlin[(c0 + j) * 2 + 1], o1);
  }
  o0 += __shfl_xor(o0, 1); o1 += __shfl_xor(o1, 1);
  o0 += __shfl_xor(o0, 2); o1 += __shfl_xor(o1, 2);
  if (lane == 0) {
    out[(size_t)n * 2 + 0] = o0 + blin[0];
    out[(size_t)n * 2 + 1] = o1 + blin[1];
  }
}

extern "C" void kernel_launch(void* const* d_in, const int* in_sizes, int n_in,
                              void* d_out, int out_size, void* d_ws, size_t ws_size,
                              hipStream_t stream) {
  const float* x     = (const float*)d_in[0];
  const int*   ei    = (const int*)d_in[1];
  const float* W1l   = (const float*)d_in[2];
  const float* b1l   = (const float*)d_in[3];
  const float* W1r   = (const float*)d_in[4];
  const float* b1r   = (const float*)d_in[5];
  const float* att1  = (const float*)d_in[6];
  const float* bias1 = (const float*)d_in[7];
  const float* W2l   = (const float*)d_in[8];
  const float* b2l   = (const float*)d_in[9];
  const float* W2r   = (const float*)d_in[10];
  const float* b2r   = (const float*)d_in[11];
  const float* att2  = (const float*)d_in[12];
  const float* bias2 = (const float*)d_in[13];
  const float* Wlin  = (const float*)d_in[14];
  const float* blin  = (const float*)d_in[15];
  float* out = (float*)d_out;

  // workspace layout
  __half* xl1h  = (__half*)d_ws;                        // N*128
  __half* xr1h  = xl1h + (size_t)N_NODES * 128;         // N*128
  __half* h1h   = xr1h + (size_t)N_NODES * 128;         // N*128
  __half* xl2h  = h1h + (size_t)N_NODES * 128;          // N*32
  __half* xr2h  = xl2h + (size_t)N_NODES * 32;          // N*32
  _Float16* Bperm  = (_Float16*)(xr2h + (size_t)N_NODES * 32);  // 32768
  _Float16* B2perm = Bperm + 32768;                     // 8192
  _Float16* att1h  = B2perm + 8192;                     // 128
  _Float16* att2h  = att1h + 128;                       // 32
  float* biascat   = (float*)(att2h + 32);              // 256
  float* bias2cat  = biascat + 256;                     // 64
  int* csr_src     = (int*)(bias2cat + 64);             // ETOT
  unsigned* rowptr = (unsigned*)(csr_src + (size_t)ETOT);  // N+1
  unsigned* cursor = rowptr + (N_NODES + 1);            // NREP*NB
  unsigned* bucket_base = cursor + NREP * NB;           // NB+1
  unsigned* bins   = bucket_base + NB + 1;              // NB*BCAP (~8.8 MB)

  // ---- CSR chain + prep (bin || pack fused) ----
  (void)hipMemsetAsync(cursor, 0, (size_t)NREP * NB * sizeof(unsigned), stream);
  fusedA_kernel<<<NCHB + 20, 256, 0, stream>>>(
      ei, cursor, bins, W1l, W1r, b1l, b1r, W2l, W2r, b2l, b2r, att1, att2,
      Bperm, B2perm, biascat, bias2cat, att1h, att2h);
  scan_buckets<<<1, 1024, 0, stream>>>(cursor, bucket_base, rowptr);
  // ---- scatter || gemm1 fused ----
  fusedB_kernel<<<NB + GEMM1_BLOCKS, 256, 0, stream>>>(
      bins, cursor, bucket_base, rowptr, csr_src, x, Bperm, biascat, xl1h, xr1h);

  // ---- layer 1 gather ----
  l1_gather_kernel<<<(N_NODES + 3) / 4, 256, 0, stream>>>(
      (const __half*)xl1h, (const __half*)xr1h, csr_src, rowptr, att1h, bias1, h1h);

  // ---- layer 2 + final linear ----
  gemm2_mfma<<<GEMM1_BLOCKS, 256, 0, stream>>>(h1h, B2perm, bias2cat, xl2h, xr2h);
  l2_gather_kernel<<<(N_NODES + 3) / 4, 256, 0, stream>>>(
      xl2h, xr2h, csr_src, rowptr, att2h, bias2, Wlin, blin, out);
}